// Round 13
// baseline (225.551 us; speedup 1.0000x reference)
//
#include <hip/hip_runtime.h>
#include <hip/hip_bf16.h>
#include <math.h>

#define B_ 8
#define T_ 1024
#define D_ 512
#define PRED 256
#define TP (T_ + PRED)
#define NH 8
#define DH 64
#define DFF 2048
#define CO 64
#define KSEL 8

typedef __hip_bfloat16 bf16;
using bf16x8 = __attribute__((ext_vector_type(8))) short;
using f32x4  = __attribute__((ext_vector_type(4))) float;

__device__ __forceinline__ void gload_lds16(const void* gp, void* lp) {
  __builtin_amdgcn_global_load_lds(
      (const __attribute__((address_space(1))) void*)gp,
      (__attribute__((address_space(3))) void*)lp, 16, 0, 0);
}

// counted vmem wait (N = loads allowed to stay in flight)
template <int N>
__device__ __forceinline__ void vm_wait() {
  if constexpr (N == 0)      asm volatile("s_waitcnt vmcnt(0)" ::: "memory");
  else if constexpr (N == 2) asm volatile("s_waitcnt vmcnt(2)" ::: "memory");
  else if constexpr (N == 4) asm volatile("s_waitcnt vmcnt(4)" ::: "memory");
  else if constexpr (N == 6) asm volatile("s_waitcnt vmcnt(6)" ::: "memory");
  else if constexpr (N == 8) asm volatile("s_waitcnt vmcnt(8)" ::: "memory");
  else static_assert(N == 0, "unsupported vmcnt literal");
}

// ---------------- transpose res (b,T,D) -> resT (b,D,T) ----------------
__global__ __launch_bounds__(256) void k_transpose(const float* __restrict__ in, float* __restrict__ out) {
  __shared__ float tile[32][33];
  const int b = blockIdx.z;
  const int d0 = blockIdx.x * 32, t0 = blockIdx.y * 32;
  const int tx = threadIdx.x, ty = threadIdx.y;
  const float* src = in + ((size_t)b * T_ + t0) * D_ + d0;
#pragma unroll
  for (int i = 0; i < 32; i += 8) tile[ty + i][tx] = src[(size_t)(ty + i) * D_ + tx];
  __syncthreads();
  float* dst = out + ((size_t)b * D_ + d0) * T_ + t0;
#pragma unroll
  for (int i = 0; i < 32; i += 8) dst[(size_t)(ty + i) * T_ + tx] = tile[tx][ty + i];
}

// ---------------- 1024-pt real FFT per (b,d) + top-8 bins ----------------
// Top-k: wave-local (registers, shuffle-reduce, 0 barriers) then single cross-wave
// merge by wave 0 — 3 barriers total vs 16 in the per-round block-wide scheme.
__global__ __launch_bounds__(256) void k_fft_topk(const float* __restrict__ xt, float* __restrict__ comp) {
  __shared__ float2 bA[512], bB[512], tw[256];
  __shared__ float xre[512], xim[512], mag2[512];
  __shared__ float wtv[4][8];
  __shared__ int wti[4][8];
  __shared__ int selk[KSEL];
  const int j = threadIdx.x;
  const int bd = blockIdx.x;
  {
    const float ang = -(6.283185307179586f / 512.0f) * (float)j;
    tw[j] = make_float2(__cosf(ang), __sinf(ang));
  }
  const float4 v4 = ((const float4*)(xt + (size_t)bd * 1024))[j];
  bA[2 * j] = make_float2(v4.x, v4.y);
  bA[2 * j + 1] = make_float2(v4.z, v4.w);
  __syncthreads();
#pragma unroll
  for (int st = 0; st < 9; ++st) {
    const int s = 1 << st;
    const int p = j >> st;
    const int q = j & (s - 1);
    const int m = 256 >> st;
    float2 a, b2;
    if ((st & 1) == 0) { a = bA[q + s * p]; b2 = bA[q + s * (p + m)]; }
    else               { a = bB[q + s * p]; b2 = bB[q + s * (p + m)]; }
    const float2 w = tw[p << st];
    float2 d0 = make_float2(a.x + b2.x, a.y + b2.y);
    const float ex = a.x - b2.x, ey = a.y - b2.y;
    float2 d1 = make_float2(ex * w.x - ey * w.y, ex * w.y + ey * w.x);
    if ((st & 1) == 0) { bB[q + s * 2 * p] = d0; bB[q + s * (2 * p + 1)] = d1; }
    else               { bA[q + s * 2 * p] = d0; bA[q + s * (2 * p + 1)] = d1; }
    __syncthreads();
  }
#pragma unroll
  for (int u = 0; u < 2; ++u) {
    const int k = (u == 0) ? (j + 1) : (j + 257);
    if (k <= 511) {
      const float2 zk = bB[k & 511];
      const float2 zm = bB[(512 - k) & 511];
      const float Ex = 0.5f * (zk.x + zm.x), Ey = 0.5f * (zk.y - zm.y);
      const float Ox = 0.5f * (zk.y + zm.y), Oy = 0.5f * (zm.x - zk.x);
      const float ang = -(6.283185307179586f / 1024.0f) * (float)k;
      const float cs = __cosf(ang), sn = __sinf(ang);
      const float Xr = Ex + cs * Ox - sn * Oy;
      const float Xi = Ey + cs * Oy + sn * Ox;
      xre[k] = Xr; xim[k] = Xi; mag2[k] = Xr * Xr + Xi * Xi;
    }
  }
  if (j == 0) mag2[0] = -1.0f;
  __syncthreads();
  // ---- wave-local top-8 over 128 owned bins (registers, no barriers) ----
  const int lane = j & 63, wq = j >> 6;
  const int b0 = wq * 128 + lane;
  const int b1 = wq * 128 + 64 + lane;
  float v0 = mag2[b0], v1 = mag2[b1];
#pragma unroll
  for (int r = 0; r < KSEL; ++r) {
    float bv = v0;
    int bk = b0;
    if (v1 > bv) { bv = v1; bk = b1; }   // equal -> keep b0 (smaller idx)
#pragma unroll
    for (int off = 32; off; off >>= 1) {
      const float ov = __shfl_down(bv, off);
      const int ok = __shfl_down(bk, off);
      if (ov > bv || (ov == bv && ok < bk)) { bv = ov; bk = ok; }
    }
    bk = __shfl(bk, 0);
    bv = __shfl(bv, 0);
    if (lane == 0) { wtv[wq][r] = bv; wti[wq][r] = bk; }
    if (b0 == bk) v0 = -2.0f;
    if (b1 == bk) v1 = -2.0f;
  }
  __syncthreads();
  // ---- wave 0 merges 4x8 = 32 candidates ----
  if (wq == 0) {
    float cv = -3.0f;
    int ck = 1 << 30;
    if (lane < 32) { cv = wtv[lane >> 3][lane & 7]; ck = wti[lane >> 3][lane & 7]; }
#pragma unroll
    for (int r = 0; r < KSEL; ++r) {
      float bv = cv;
      int bk = ck;
#pragma unroll
      for (int off = 32; off; off >>= 1) {
        const float ov = __shfl_down(bv, off);
        const int ok = __shfl_down(bk, off);
        if (ov > bv || (ov == bv && ok < bk)) { bv = ov; bk = ok; }
      }
      bk = __shfl(bk, 0);
      if (lane == 0) selk[r] = bk;
      if (ck == bk) cv = -3.0f;
    }
  }
  __syncthreads();
  if (j < KSEL) {
    const int k = selk[j];
    const float re = xre[k], im = xim[k];
    float* o = comp + (size_t)bd * 24 + j * 3;
    o[0] = 2.0f * sqrtf(re * re + im * im) * (1.0f / 1024.0f);
    o[1] = (float)k;
    o[2] = atan2f(im, re);
  }
}

// ---------------- season synthesis + res1 = res - season ----------------
__global__ __launch_bounds__(512) void k_season(const float* __restrict__ comp, const float* __restrict__ res,
                                                float* __restrict__ season, bf16* __restrict__ res1b,
                                                bf16* __restrict__ seasb) {
  const int d = threadIdx.x;
  const int b = blockIdx.y;
  const int t0 = blockIdx.x * 5;
  float a_[8], kf_[8], ph_[8];
  const float* c = comp + ((size_t)b * 512 + d) * 24;
#pragma unroll
  for (int i = 0; i < 8; i++) { a_[i] = c[3 * i]; kf_[i] = c[3 * i + 1]; ph_[i] = c[3 * i + 2]; }
#pragma unroll
  for (int tt = 0; tt < 5; ++tt) {
    const int t = t0 + tt;
    float acc = 0.0f;
#pragma unroll
    for (int i = 0; i < 8; i++) {
      float fr = kf_[i] * (float)t * (1.0f / 1024.0f);
      fr -= floorf(fr);
      acc += a_[i] * __cosf(fmaf(6.283185307179586f, fr, ph_[i]));
    }
    season[((size_t)b * TP + t) * D_ + d] = acc;
    if (t < T_) {
      const float rr = res[((size_t)b * T_ + t) * D_ + d] - acc;
      res1b[((size_t)b * T_ + t) * D_ + d] = __float2bfloat16(rr);
      seasb[((size_t)b * T_ + t) * D_ + d] = __float2bfloat16(acc);
    }
  }
}

// ---------------- fused f32 -> bf16 for all 6 weight tensors ----------------
#define CVT_TOTAL 2686976
__global__ __launch_bounds__(256) void k_cvt_all(const float* __restrict__ s0, const float* __restrict__ s1,
                                                 const float* __restrict__ s2_, const float* __restrict__ s3,
                                                 const float* __restrict__ s4, const float* __restrict__ s5,
                                                 bf16* __restrict__ dst) {
  const int i = (blockIdx.x * 256 + threadIdx.x) * 4;
  if (i >= CVT_TOTAL) return;
  const float* src;
  int off;
  if (i < 262144)       { src = s0;  off = i; }
  else if (i < 524288)  { src = s1;  off = i - 262144; }
  else if (i < 1572864) { src = s2_; off = i - 524288; }
  else if (i < 2621440) { src = s3;  off = i - 1572864; }
  else if (i < 2654208) { src = s4;  off = i - 2621440; }
  else                  { src = s5;  off = i - 2654208; }
  const float4 v = *(const float4*)(src + off);
  bf16* o = dst + i;
  o[0] = __float2bfloat16(v.x); o[1] = __float2bfloat16(v.y);
  o[2] = __float2bfloat16(v.z); o[3] = __float2bfloat16(v.w);
}

// ---------------- growth exp-smooth blocked scan ----------------
__global__ __launch_bounds__(1024) void k_growth_scan2(const float* __restrict__ v, const float* __restrict__ z0,
                                                       const float* __restrict__ sw, const float* __restrict__ v0,
                                                       bf16* __restrict__ s2) {
  const int b = blockIdx.x >> 3;
  const int col = (blockIdx.x & 7) * 64 + (threadIdx.x & 63);
  const int w = threadIdx.x >> 6;
  const float alpha = 1.0f / (1.0f + expf(-sw[col >> 6]));
  const float om = 1.0f - alpha;
  float a64 = alpha;
#pragma unroll
  for (int i = 0; i < 6; i++) a64 *= a64;
  const float* vp = v + (size_t)b * T_ * D_ + col;
  float vprev = (w == 0) ? z0[col] : vp[(size_t)(64 * w - 1) * D_];
  float sloc = 0.0f;
#pragma unroll 8
  for (int j = 0; j < 64; j++) {
    const float nv = vp[(size_t)(64 * w + j) * D_];
    sloc = alpha * sloc + om * (nv - vprev);
    vprev = nv;
  }
  __shared__ float lb[16][64], lc[16][64];
  lb[w][threadIdx.x & 63] = sloc;
  __syncthreads();
  if (w == 0) {
    float s = v0[col];
#pragma unroll
    for (int k = 0; k < 16; k++) { lc[k][threadIdx.x & 63] = s; s = a64 * s + lb[k][threadIdx.x & 63]; }
  }
  __syncthreads();
  float s = lc[w][threadIdx.x & 63];
  vprev = (w == 0) ? z0[col] : vp[(size_t)(64 * w - 1) * D_];
  bf16* op = s2 + (size_t)b * (T_ + 1) * D_ + col;
  if (w == 0) op[0] = __float2bfloat16(v0[col]);
#pragma unroll 8
  for (int j = 0; j < 64; j++) {
    const float nv = vp[(size_t)(64 * w + j) * D_];
    s = alpha * s + om * (nv - vprev);
    vprev = nv;
    op[(size_t)(64 * w + j + 1) * D_] = __float2bfloat16(s);
  }
}

// ---------------- level exp-smooth blocked scan ----------------
__global__ __launch_bounds__(1024) void k_level_scan2(const float* __restrict__ level, const float* __restrict__ gp,
                                                      const float* __restrict__ sp, const float* __restrict__ sw,
                                                      const float* __restrict__ v0, float* __restrict__ out) {
  const int b = blockIdx.x;
  const int w = threadIdx.x >> 6;
  const int c = threadIdx.x & 63;
  const float alpha = 1.0f / (1.0f + expf(-sw[c]));
  const float om = 1.0f - alpha;
  float a64 = alpha;
#pragma unroll
  for (int i = 0; i < 6; i++) a64 *= a64;
  const size_t base = ((size_t)b * T_ + 64 * w) * CO + c;
  float sloc = 0.0f;
#pragma unroll 8
  for (int j = 0; j < 64; j++) {
    const size_t idx = base + (size_t)j * CO;
    const float u = om * (level[idx] - sp[idx]) + alpha * gp[idx];
    out[idx] = u;
    sloc = alpha * sloc + u;
  }
  __shared__ float lb[16][64], lc[16][64];
  lb[w][c] = sloc;
  __syncthreads();
  if (w == 0) {
    float s = v0[c];
#pragma unroll
    for (int k = 0; k < 16; k++) { lc[k][c] = s; s = a64 * s + lb[k][c]; }
  }
  __syncthreads();
  float s = lc[w][c];
#pragma unroll 8
  for (int j = 0; j < 64; j++) {
    const size_t idx = base + (size_t)j * CO;
    s = alpha * s + out[idx];
    out[idx] = s;
  }
}

// ---------------- layer norm over D=512 ----------------
template <int MODE>
__global__ __launch_bounds__(128) void k_ln(const float* __restrict__ x1, const float* __restrict__ x2,
                                            const float* __restrict__ x3, const float* __restrict__ g,
                                            const float* __restrict__ be, float* __restrict__ outF,
                                            bf16* __restrict__ outB) {
  const int m = blockIdx.x, tid = threadIdx.x;
  const int b = m >> 10;
  float4 v = ((const float4*)(x1 + (size_t)m * D_))[tid];
  if (MODE == 0) {
    const float4 se = ((const float4*)(x2 + ((size_t)(m + b * PRED)) * D_))[tid];
    const float4 gr = ((const float4*)(x3 + ((size_t)(m + b + 1)) * D_))[tid];
    v.x -= se.x + gr.x; v.y -= se.y + gr.y; v.z -= se.z + gr.z; v.w -= se.w + gr.w;
  }
  float s = v.x + v.y + v.z + v.w;
  float s2 = v.x * v.x + v.y * v.y + v.z * v.z + v.w * v.w;
#pragma unroll
  for (int off = 32; off; off >>= 1) { s += __shfl_down(s, off); s2 += __shfl_down(s2, off); }
  __shared__ float p1[2], p2[2];
  if ((tid & 63) == 0) { p1[tid >> 6] = s; p2[tid >> 6] = s2; }
  __syncthreads();
  const float S = p1[0] + p1[1], S2 = p2[0] + p2[1];
  const float mu = S * (1.0f / 512.0f);
  const float rs = rsqrtf(fmaxf(S2 * (1.0f / 512.0f) - mu * mu, 0.0f) + 1e-5f);
  const float4 gg = ((const float4*)g)[tid], bb = ((const float4*)be)[tid];
  float4 o;
  o.x = (v.x - mu) * rs * gg.x + bb.x;
  o.y = (v.y - mu) * rs * gg.y + bb.y;
  o.z = (v.z - mu) * rs * gg.z + bb.z;
  o.w = (v.w - mu) * rs * gg.w + bb.w;
  ((float4*)(outF + (size_t)m * D_))[tid] = o;
  if (MODE == 0) {
    bf16* ob = outB + (size_t)m * D_ + tid * 4;
    ob[0] = __float2bfloat16(o.x); ob[1] = __float2bfloat16(o.y);
    ob[2] = __float2bfloat16(o.z); ob[3] = __float2bfloat16(o.w);
  }
}

// ---------------- bf16 MFMA GEMM, swizzled LDS + counted-vmcnt pipeline ----------------
// tm = blockIdx.x (FASTEST dispatch index): same-tm blocks (sharing the A row-panel)
// get dispatch ids congruent mod NXCD -> co-locate on one XCD's L2 (A staged as L2 hit).
template <int BM, int BN, int BK, int WM, int WN, int EPI, bool DUAL = false>
__global__ __launch_bounds__(WM * WN * 64, 2) void k_gemm(
    const bf16* __restrict__ A, const bf16* __restrict__ Bw,
    const float* __restrict__ bias, float* outF, bf16* __restrict__ outB,
    const float* resid, const int M, const int N, const int K, int extra,
    const bf16* __restrict__ A2, const bf16* __restrict__ Bw2,
    const float* __restrict__ bias2, float* outF2, int extra2) {
  constexpr int NW = WM * WN;
  constexpr int FM = BM / (WM * 16);
  constexpr int FN = BN / (WN * 16);
  constexpr int RPC = 512 / BK;
  constexpr int LA = (BM / RPC) / NW, LB = (BN / RPC) / NW;
  constexpr int KK = BK / 32;
  constexpr int TLOADS = LA + LB;
  static_assert(LA >= 1 && LB >= 1, "tile too small for staging split");
  static_assert((BM / RPC) % NW == 0 && (BN / RPC) % NW == 0, "staging split");
  if constexpr (DUAL) {
    if (blockIdx.z == 1) { A = A2; Bw = Bw2; bias = bias2; outF = outF2; extra = extra2; }
  }
  __shared__ bf16 lsA[2][BM * BK];
  __shared__ bf16 lsB[2][BN * BK];
  const int tid = threadIdx.x;
  const int w = tid >> 6, lane = tid & 63;
  const int tm = blockIdx.x, tn = blockIdx.y;   // tm fastest -> XCD A-locality
  const int wr = w / WN, wc = w % WN;
  const int r16 = lane & 15, hi = lane >> 4;

  int srowoff, scoloff;
  if constexpr (BK == 64) {
    const int rr = lane >> 3, cs = lane & 7;
    srowoff = rr;
    scoloff = (cs ^ rr) * 8;
  } else {
    const int sr = lane >> 3, cs = lane & 7;
    const int idx = cs ^ (sr & 7);
    srowoff = sr * 2 + (idx >> 2);
    scoloff = (idx & 3) * 8;
  }

  const f32x4 fzero = {0.f, 0.f, 0.f, 0.f};
  f32x4 acc[FM][FN];
#pragma unroll
  for (int i = 0; i < FM; i++)
#pragma unroll
    for (int jj = 0; jj < FN; jj++) acc[i][jj] = fzero;

  const int NT = K / BK;

  auto stage = [&](int kt, int sel) {
#pragma unroll
    for (int q = 0; q < LA; q++) {
      const int g = w * LA + q;
      int m = tm * BM + g * RPC + srowoff;
      if (m > M - 1) m = M - 1;
      m += (m >> 10) * extra;
      gload_lds16(A + (size_t)m * K + (size_t)kt * BK + scoloff, &lsA[sel][g * 512]);
    }
#pragma unroll
    for (int q = 0; q < LB; q++) {
      const int g = w * LB + q;
      const int n = tn * BN + g * RPC + srowoff;
      gload_lds16(Bw + (size_t)n * K + (size_t)kt * BK + scoloff, &lsB[sel][g * 512]);
    }
  };

  auto frag = [&](const bf16* ls, int row, int cc) -> bf16x8 {
    if constexpr (BK == 64) {
      const int g = row >> 3, rr = row & 7;
      return *(const bf16x8*)&ls[g * 512 + rr * 64 + ((cc ^ rr) << 3)];
    } else {
      const int g = row >> 4, rr = row & 15, sr = rr >> 1;
      const int idx = ((rr & 1) << 2) | cc;
      return *(const bf16x8*)&ls[g * 512 + sr * 64 + ((idx ^ (sr & 7)) << 3)];
    }
  };

  stage(0, 0);
  for (int kt = 0; kt < NT; ++kt) {
    const int sel = kt & 1;
    if (kt + 1 < NT) {
      stage(kt + 1, sel ^ 1);
      vm_wait<TLOADS>();
    } else {
      vm_wait<0>();
    }
    __builtin_amdgcn_sched_barrier(0);
    __builtin_amdgcn_s_barrier();
    __builtin_amdgcn_sched_barrier(0);
#pragma unroll
    for (int kk = 0; kk < KK; ++kk) {
      bf16x8 af[FM], bfv[FN];
#pragma unroll
      for (int i = 0; i < FM; i++)
        af[i] = frag(lsA[sel], wr * (FM * 16) + i * 16 + r16, kk * 4 + hi);
#pragma unroll
      for (int jj = 0; jj < FN; jj++)
        bfv[jj] = frag(lsB[sel], wc * (FN * 16) + jj * 16 + r16, kk * 4 + hi);
#pragma unroll
      for (int i = 0; i < FM; i++)
#pragma unroll
        for (int jj = 0; jj < FN; jj++)
          acc[i][jj] = __builtin_amdgcn_mfma_f32_16x16x32_bf16(af[i], bfv[jj], acc[i][jj], 0, 0, 0);
    }
    if (kt + 1 < NT) {
      __builtin_amdgcn_sched_barrier(0);
      __builtin_amdgcn_s_barrier();
      __builtin_amdgcn_sched_barrier(0);
    }
  }

#pragma unroll
  for (int i = 0; i < FM; i++) {
#pragma unroll
    for (int r = 0; r < 4; r++) {
      const int m = tm * BM + wr * (FM * 16) + i * 16 + hi * 4 + r;
      if (m < M) {
#pragma unroll
        for (int jj = 0; jj < FN; jj++) {
          const int n = tn * BN + wc * (FN * 16) + jj * 16 + r16;
          float x = acc[i][jj][r];
          if (bias) x += bias[n];
          const size_t idx = (size_t)m * N + n;
          if (EPI == 0) {
            outF[idx] = x;
          } else if (EPI == 1) {
            outF[idx] = x;
            outB[idx] = __float2bfloat16(x);
          } else if (EPI == 2) {
            outB[idx] = __float2bfloat16(1.0f / (1.0f + __expf(-x)));
          } else {
            outF[idx] = x + resid[idx];
          }
        }
      }
    }
  }
}

// ---------------- workspace layout ----------------
#define MB (size_t)(1u << 20)
static const size_t OFF_A = 0;
static const size_t OFF_C = 32 * MB;
static const size_t OFF_D = 40 * MB;
static const size_t OFF_E = 48 * MB;
static const size_t OFF_F = 54 * MB;
static const size_t OFF_G = 63 * MB;
static const size_t OFF_H = 72 * MB;
static const size_t OFF_J = 88 * MB;
static const size_t OFF_K = 89 * MB;
static const size_t OFF_K2 = 91 * MB;

#define W_IN 0
#define W_OUT 262144
#define W_FF1 524288
#define W_FF2 1572864
#define W_GW 2621440
#define W_SW2 2654208

extern "C" void kernel_launch(void* const* d_in, const int* in_sizes, int n_in, void* d_out, int out_size,
                              void* d_ws, size_t ws_size, hipStream_t stream) {
  (void)in_sizes; (void)n_in; (void)out_size; (void)ws_size;
  const float* res = (const float*)d_in[0];
  const float* level = (const float*)d_in[1];
  const float* gl_z0 = (const float*)d_in[2];
  const float* gl_in_w = (const float*)d_in[3];
  const float* gl_in_b = (const float*)d_in[4];
  const float* gl_sw = (const float*)d_in[5];
  const float* gl_v0 = (const float*)d_in[6];
  const float* gl_out_w = (const float*)d_in[7];
  const float* gl_out_b = (const float*)d_in[8];
  const float* ll_sw = (const float*)d_in[9];
  const float* ll_v0 = (const float*)d_in[10];
  const float* ll_gw = (const float*)d_in[11];
  const float* ll_gb = (const float*)d_in[12];
  const float* ll_sw2 = (const float*)d_in[13];
  const float* ll_sb = (const float*)d_in[14];
  const float* ff_w1 = (const float*)d_in[15];
  const float* ff_w2 = (const float*)d_in[16];
  const float* n1_g = (const float*)d_in[17];
  const float* n1_b = (const float*)d_in[18];
  const float* n2_g = (const float*)d_in[19];
  const float* n2_b = (const float*)d_in[20];

  char* ws = (char*)d_ws;
  float* resT = (float*)(ws + OFF_A);
  float* vbuf = (float*)(ws + OFF_A);
  bf16* hbuf = (bf16*)(ws + OFF_A);
  bf16* res1b = (bf16*)(ws + OFF_C);
  bf16* res2b = (bf16*)(ws + OFF_C);
  bf16* seasb = (bf16*)(ws + OFF_D);
  bf16* wE = (bf16*)(ws + OFF_E);
  bf16* s2b = (bf16*)(ws + OFF_F);
  bf16* grob = (bf16*)(ws + OFF_G);
  float* res2f = (float*)(ws + OFF_H);
  float* comp = (float*)(ws + OFF_J);
  float* gproj = (float*)(ws + OFF_K);
  float* sproj = (float*)(ws + OFF_K2);

  float* o_res = (float*)d_out;
  float* o_level = o_res + 4194304;
  float* o_growth = o_level + 524288;
  float* o_season = o_growth + 4198400;

  k_transpose<<<dim3(16, 32, 8), dim3(32, 8), 0, stream>>>(res, resT);
  k_fft_topk<<<4096, 256, 0, stream>>>(resT, comp);
  k_season<<<dim3(256, 8), 512, 0, stream>>>(comp, res, o_season, res1b, seasb);
  k_cvt_all<<<(CVT_TOTAL / 4 + 255) / 256, 256, 0, stream>>>(gl_in_w, gl_out_w, ff_w1, ff_w2, ll_gw, ll_sw2, wE);
  // v = res1 @ gl_in_w^T + b   (64x128, BK=64, 4 waves; tm-fastest grid)
  k_gemm<64, 128, 64, 2, 2, 0><<<dim3(128, 4), 256, 0, stream>>>(
      res1b, wE + W_IN, gl_in_b, vbuf, nullptr, nullptr, 8192, 512, 512, 0,
      nullptr, nullptr, nullptr, nullptr, 0);
  k_growth_scan2<<<64, 1024, 0, stream>>>(vbuf, gl_z0, gl_sw, gl_v0, s2b);
  // growth = s2 @ gl_out_w^T + b
  k_gemm<64, 128, 64, 2, 2, 1><<<dim3(129, 4), 256, 0, stream>>>(
      s2b, wE + W_OUT, gl_out_b, o_growth, grob, nullptr, 8200, 512, 512, 0,
      nullptr, nullptr, nullptr, nullptr, 0);
  k_ln<0><<<8192, 128, 0, stream>>>(res, o_season, o_growth, n1_g, n1_b, res2f, res2b);
  // FF1: 128x128 BK=32, 4 waves, tm-fastest grid
  k_gemm<128, 128, 32, 2, 2, 2><<<dim3(64, 16), 256, 0, stream>>>(
      res2b, wE + W_FF1, nullptr, nullptr, hbuf, nullptr, 8192, 2048, 512, 0,
      nullptr, nullptr, nullptr, nullptr, 0);
  // FF2: 64x128 BK=64, K=2048
  k_gemm<64, 128, 64, 2, 2, 3><<<dim3(128, 4), 256, 0, stream>>>(
      hbuf, wE + W_FF2, nullptr, res2f, nullptr, res2f, 8192, 512, 2048, 0,
      nullptr, nullptr, nullptr, nullptr, 0);
  k_ln<1><<<8192, 128, 0, stream>>>(res2f, nullptr, nullptr, n2_g, n2_b, o_res, nullptr);
  // gproj & sproj merged: one dual dispatch (z=0: growth@ll_gw; z=1: season@ll_sw2)
  k_gemm<64, 64, 64, 4, 1, 0, true><<<dim3(128, 1, 2), 256, 0, stream>>>(
      grob, wE + W_GW, ll_gb, gproj, nullptr, nullptr, 8192, 64, 512, 1,
      seasb, wE + W_SW2, ll_sb, sproj, 0);
  k_level_scan2<<<8, 1024, 0, stream>>>(level, gproj, sproj, ll_sw, ll_v0, o_level);
}

// Round 14
// 220.009 us; speedup vs baseline: 1.0252x; 1.0252x over previous
//
#include <hip/hip_runtime.h>
#include <hip/hip_bf16.h>
#include <math.h>

#define B_ 8
#define T_ 1024
#define D_ 512
#define PRED 256
#define TP (T_ + PRED)
#define NH 8
#define DH 64
#define DFF 2048
#define CO 64
#define KSEL 8

typedef __hip_bfloat16 bf16;
using bf16x8 = __attribute__((ext_vector_type(8))) short;
using f32x4  = __attribute__((ext_vector_type(4))) float;

__device__ __forceinline__ void gload_lds16(const void* gp, void* lp) {
  __builtin_amdgcn_global_load_lds(
      (const __attribute__((address_space(1))) void*)gp,
      (__attribute__((address_space(3))) void*)lp, 16, 0, 0);
}

// counted vmem wait (N = loads allowed to stay in flight)
template <int N>
__device__ __forceinline__ void vm_wait() {
  if constexpr (N == 0)      asm volatile("s_waitcnt vmcnt(0)" ::: "memory");
  else if constexpr (N == 2) asm volatile("s_waitcnt vmcnt(2)" ::: "memory");
  else if constexpr (N == 4) asm volatile("s_waitcnt vmcnt(4)" ::: "memory");
  else if constexpr (N == 6) asm volatile("s_waitcnt vmcnt(6)" ::: "memory");
  else if constexpr (N == 8) asm volatile("s_waitcnt vmcnt(8)" ::: "memory");
  else static_assert(N == 0, "unsupported vmcnt literal");
}

// ---------------- transpose res (b,T,D) -> resT (b,D,T) ----------------
__global__ __launch_bounds__(256) void k_transpose(const float* __restrict__ in, float* __restrict__ out) {
  __shared__ float tile[32][33];
  const int b = blockIdx.z;
  const int d0 = blockIdx.x * 32, t0 = blockIdx.y * 32;
  const int tx = threadIdx.x, ty = threadIdx.y;
  const float* src = in + ((size_t)b * T_ + t0) * D_ + d0;
#pragma unroll
  for (int i = 0; i < 32; i += 8) tile[ty + i][tx] = src[(size_t)(ty + i) * D_ + tx];
  __syncthreads();
  float* dst = out + ((size_t)b * D_ + d0) * T_ + t0;
#pragma unroll
  for (int i = 0; i < 32; i += 8) dst[(size_t)(ty + i) * T_ + tx] = tile[tx][ty + i];
}

// ---------------- 1024-pt real FFT, 2 series per block, + top-8 bins ----------------
// Two independent FFTs share each stage's barrier (half the barriers per FFT, 2x ILP).
// mag2 overlays the dead bufA after the last stage; re/im recomputed from bufB at output.
// Top-k: round-12-proven block-wide scheme, both series reduced in the same rounds.
__global__ __launch_bounds__(256) void k_fft_topk(const float* __restrict__ xt, float* __restrict__ comp) {
  __shared__ float2 bufA[2][512], bufB[2][512], tw[256];
  __shared__ float wvv[2][4];
  __shared__ int wkk[2][4];
  __shared__ int selk[2][KSEL];
  float* const mg0 = (float*)&bufA[0][0];
  float* const mg1 = (float*)&bufA[1][0];
  const int j = threadIdx.x;
  const size_t bd0 = (size_t)blockIdx.x * 2;
  {
    const float ang = -(6.283185307179586f / 512.0f) * (float)j;
    tw[j] = make_float2(__cosf(ang), __sinf(ang));
  }
  const float4 u0 = ((const float4*)(xt + bd0 * 1024))[j];
  const float4 u1 = ((const float4*)(xt + (bd0 + 1) * 1024))[j];
  bufA[0][2 * j] = make_float2(u0.x, u0.y); bufA[0][2 * j + 1] = make_float2(u0.z, u0.w);
  bufA[1][2 * j] = make_float2(u1.x, u1.y); bufA[1][2 * j + 1] = make_float2(u1.z, u1.w);
  __syncthreads();
#pragma unroll
  for (int st = 0; st < 9; ++st) {
    const int s = 1 << st, p = j >> st, q = j & (s - 1), m = 256 >> st;
    const int ia = q + s * p, ib = q + s * (p + m);
    const int oa = q + s * 2 * p, ob = q + s * (2 * p + 1);
    float2 a0, b0, a1, b1;
    if ((st & 1) == 0) { a0 = bufA[0][ia]; b0 = bufA[0][ib]; a1 = bufA[1][ia]; b1 = bufA[1][ib]; }
    else               { a0 = bufB[0][ia]; b0 = bufB[0][ib]; a1 = bufB[1][ia]; b1 = bufB[1][ib]; }
    const float2 w = tw[p << st];
    const float2 s0 = make_float2(a0.x + b0.x, a0.y + b0.y);
    const float ex0 = a0.x - b0.x, ey0 = a0.y - b0.y;
    const float2 d0 = make_float2(ex0 * w.x - ey0 * w.y, ex0 * w.y + ey0 * w.x);
    const float2 s1 = make_float2(a1.x + b1.x, a1.y + b1.y);
    const float ex1 = a1.x - b1.x, ey1 = a1.y - b1.y;
    const float2 d1 = make_float2(ex1 * w.x - ey1 * w.y, ex1 * w.y + ey1 * w.x);
    if ((st & 1) == 0) { bufB[0][oa] = s0; bufB[0][ob] = d0; bufB[1][oa] = s1; bufB[1][ob] = d1; }
    else               { bufA[0][oa] = s0; bufA[0][ob] = d0; bufA[1][oa] = s1; bufA[1][ob] = d1; }
    __syncthreads();
  }
  // result Z in bufB (stage 8 even); bufA dead -> mag2 overlay
#pragma unroll
  for (int u = 0; u < 2; ++u) {
    const int k = (u == 0) ? (j + 1) : (j + 257);
    if (k <= 511) {
#pragma unroll
      for (int sx = 0; sx < 2; ++sx) {
        const float2 zk = bufB[sx][k & 511];
        const float2 zm = bufB[sx][(512 - k) & 511];
        const float Ex = 0.5f * (zk.x + zm.x), Ey = 0.5f * (zk.y - zm.y);
        const float Ox = 0.5f * (zk.y + zm.y), Oy = 0.5f * (zm.x - zk.x);
        const float ang = -(6.283185307179586f / 1024.0f) * (float)k;
        const float cs = __cosf(ang), sn = __sinf(ang);
        const float Xr = Ex + cs * Ox - sn * Oy;
        const float Xi = Ey + cs * Oy + sn * Ox;
        ((sx == 0) ? mg0 : mg1)[k] = Xr * Xr + Xi * Xi;
      }
    }
  }
  if (j == 0) { mg0[0] = -1.0f; mg1[0] = -1.0f; }
  __syncthreads();
  const int lane = j & 63, wvi = j >> 6;
  for (int r = 0; r < KSEL; ++r) {
    float bv0 = mg0[j]; int bk0 = j;
    { const float t = mg0[j + 256]; if (t > bv0) { bv0 = t; bk0 = j + 256; } }
    float bv1 = mg1[j]; int bk1 = j;
    { const float t = mg1[j + 256]; if (t > bv1) { bv1 = t; bk1 = j + 256; } }
#pragma unroll
    for (int off = 32; off; off >>= 1) {
      const float ov0 = __shfl_down(bv0, off); const int ok0 = __shfl_down(bk0, off);
      if (ov0 > bv0 || (ov0 == bv0 && ok0 < bk0)) { bv0 = ov0; bk0 = ok0; }
      const float ov1 = __shfl_down(bv1, off); const int ok1 = __shfl_down(bk1, off);
      if (ov1 > bv1 || (ov1 == bv1 && ok1 < bk1)) { bv1 = ov1; bk1 = ok1; }
    }
    if (lane == 0) { wvv[0][wvi] = bv0; wkk[0][wvi] = bk0; wvv[1][wvi] = bv1; wkk[1][wvi] = bk1; }
    __syncthreads();
    if (lane == 0 && j < 128) {  // j==0 -> series 0, j==64 -> series 1 (parallel merges)
      const int sx = j >> 6;
      float fv = wvv[sx][0];
      int fk = wkk[sx][0];
#pragma unroll
      for (int i = 1; i < 4; i++)
        if (wvv[sx][i] > fv || (wvv[sx][i] == fv && wkk[sx][i] < fk)) { fv = wvv[sx][i]; fk = wkk[sx][i]; }
      selk[sx][r] = fk;
      ((sx == 0) ? mg0 : mg1)[fk] = -2.0f;
    }
    __syncthreads();
  }
  if (j < 2 * KSEL) {
    const int sx = j >> 3, r = j & 7;
    const int k = selk[sx][r];
    const float2 zk = bufB[sx][k & 511];
    const float2 zm = bufB[sx][(512 - k) & 511];
    const float Ex = 0.5f * (zk.x + zm.x), Ey = 0.5f * (zk.y - zm.y);
    const float Ox = 0.5f * (zk.y + zm.y), Oy = 0.5f * (zm.x - zk.x);
    const float ang = -(6.283185307179586f / 1024.0f) * (float)k;
    const float cs = __cosf(ang), sn = __sinf(ang);
    const float Xr = Ex + cs * Ox - sn * Oy;
    const float Xi = Ey + cs * Oy + sn * Ox;
    float* o = comp + (bd0 + sx) * 24 + r * 3;
    o[0] = 2.0f * sqrtf(Xr * Xr + Xi * Xi) * (1.0f / 1024.0f);
    o[1] = (float)k;
    o[2] = atan2f(Xi, Xr);
  }
}

// ---------------- season synthesis + res1 = res - season ----------------
__global__ __launch_bounds__(512) void k_season(const float* __restrict__ comp, const float* __restrict__ res,
                                                float* __restrict__ season, bf16* __restrict__ res1b,
                                                bf16* __restrict__ seasb) {
  const int d = threadIdx.x;
  const int b = blockIdx.y;
  const int t0 = blockIdx.x * 5;
  float a_[8], kf_[8], ph_[8];
  const float* c = comp + ((size_t)b * 512 + d) * 24;
#pragma unroll
  for (int i = 0; i < 8; i++) { a_[i] = c[3 * i]; kf_[i] = c[3 * i + 1]; ph_[i] = c[3 * i + 2]; }
#pragma unroll
  for (int tt = 0; tt < 5; ++tt) {
    const int t = t0 + tt;
    float acc = 0.0f;
#pragma unroll
    for (int i = 0; i < 8; i++) {
      float fr = kf_[i] * (float)t * (1.0f / 1024.0f);
      fr -= floorf(fr);
      acc += a_[i] * __cosf(fmaf(6.283185307179586f, fr, ph_[i]));
    }
    season[((size_t)b * TP + t) * D_ + d] = acc;
    if (t < T_) {
      const float rr = res[((size_t)b * T_ + t) * D_ + d] - acc;
      res1b[((size_t)b * T_ + t) * D_ + d] = __float2bfloat16(rr);
      seasb[((size_t)b * T_ + t) * D_ + d] = __float2bfloat16(acc);
    }
  }
}

// ---------------- fused f32 -> bf16 for all 6 weight tensors ----------------
#define CVT_TOTAL 2686976
__global__ __launch_bounds__(256) void k_cvt_all(const float* __restrict__ s0, const float* __restrict__ s1,
                                                 const float* __restrict__ s2_, const float* __restrict__ s3,
                                                 const float* __restrict__ s4, const float* __restrict__ s5,
                                                 bf16* __restrict__ dst) {
  const int i = (blockIdx.x * 256 + threadIdx.x) * 4;
  if (i >= CVT_TOTAL) return;
  const float* src;
  int off;
  if (i < 262144)       { src = s0;  off = i; }
  else if (i < 524288)  { src = s1;  off = i - 262144; }
  else if (i < 1572864) { src = s2_; off = i - 524288; }
  else if (i < 2621440) { src = s3;  off = i - 1572864; }
  else if (i < 2654208) { src = s4;  off = i - 2621440; }
  else                  { src = s5;  off = i - 2654208; }
  const float4 v = *(const float4*)(src + off);
  bf16* o = dst + i;
  o[0] = __float2bfloat16(v.x); o[1] = __float2bfloat16(v.y);
  o[2] = __float2bfloat16(v.z); o[3] = __float2bfloat16(v.w);
}

// ---------------- growth exp-smooth blocked scan ----------------
__global__ __launch_bounds__(1024) void k_growth_scan2(const float* __restrict__ v, const float* __restrict__ z0,
                                                       const float* __restrict__ sw, const float* __restrict__ v0,
                                                       bf16* __restrict__ s2) {
  const int b = blockIdx.x >> 3;
  const int col = (blockIdx.x & 7) * 64 + (threadIdx.x & 63);
  const int w = threadIdx.x >> 6;
  const float alpha = 1.0f / (1.0f + expf(-sw[col >> 6]));
  const float om = 1.0f - alpha;
  float a64 = alpha;
#pragma unroll
  for (int i = 0; i < 6; i++) a64 *= a64;
  const float* vp = v + (size_t)b * T_ * D_ + col;
  float vprev = (w == 0) ? z0[col] : vp[(size_t)(64 * w - 1) * D_];
  float sloc = 0.0f;
#pragma unroll 8
  for (int j = 0; j < 64; j++) {
    const float nv = vp[(size_t)(64 * w + j) * D_];
    sloc = alpha * sloc + om * (nv - vprev);
    vprev = nv;
  }
  __shared__ float lb[16][64], lc[16][64];
  lb[w][threadIdx.x & 63] = sloc;
  __syncthreads();
  if (w == 0) {
    float s = v0[col];
#pragma unroll
    for (int k = 0; k < 16; k++) { lc[k][threadIdx.x & 63] = s; s = a64 * s + lb[k][threadIdx.x & 63]; }
  }
  __syncthreads();
  float s = lc[w][threadIdx.x & 63];
  vprev = (w == 0) ? z0[col] : vp[(size_t)(64 * w - 1) * D_];
  bf16* op = s2 + (size_t)b * (T_ + 1) * D_ + col;
  if (w == 0) op[0] = __float2bfloat16(v0[col]);
#pragma unroll 8
  for (int j = 0; j < 64; j++) {
    const float nv = vp[(size_t)(64 * w + j) * D_];
    s = alpha * s + om * (nv - vprev);
    vprev = nv;
    op[(size_t)(64 * w + j + 1) * D_] = __float2bfloat16(s);
  }
}

// ---------------- level exp-smooth blocked scan ----------------
__global__ __launch_bounds__(1024) void k_level_scan2(const float* __restrict__ level, const float* __restrict__ gp,
                                                      const float* __restrict__ sp, const float* __restrict__ sw,
                                                      const float* __restrict__ v0, float* __restrict__ out) {
  const int b = blockIdx.x;
  const int w = threadIdx.x >> 6;
  const int c = threadIdx.x & 63;
  const float alpha = 1.0f / (1.0f + expf(-sw[c]));
  const float om = 1.0f - alpha;
  float a64 = alpha;
#pragma unroll
  for (int i = 0; i < 6; i++) a64 *= a64;
  const size_t base = ((size_t)b * T_ + 64 * w) * CO + c;
  float sloc = 0.0f;
#pragma unroll 8
  for (int j = 0; j < 64; j++) {
    const size_t idx = base + (size_t)j * CO;
    const float u = om * (level[idx] - sp[idx]) + alpha * gp[idx];
    out[idx] = u;
    sloc = alpha * sloc + u;
  }
  __shared__ float lb[16][64], lc[16][64];
  lb[w][c] = sloc;
  __syncthreads();
  if (w == 0) {
    float s = v0[c];
#pragma unroll
    for (int k = 0; k < 16; k++) { lc[k][c] = s; s = a64 * s + lb[k][c]; }
  }
  __syncthreads();
  float s = lc[w][c];
#pragma unroll 8
  for (int j = 0; j < 64; j++) {
    const size_t idx = base + (size_t)j * CO;
    s = alpha * s + out[idx];
    out[idx] = s;
  }
}

// ---------------- layer norm over D=512 ----------------
template <int MODE>
__global__ __launch_bounds__(128) void k_ln(const float* __restrict__ x1, const float* __restrict__ x2,
                                            const float* __restrict__ x3, const float* __restrict__ g,
                                            const float* __restrict__ be, float* __restrict__ outF,
                                            bf16* __restrict__ outB) {
  const int m = blockIdx.x, tid = threadIdx.x;
  const int b = m >> 10;
  float4 v = ((const float4*)(x1 + (size_t)m * D_))[tid];
  if (MODE == 0) {
    const float4 se = ((const float4*)(x2 + ((size_t)(m + b * PRED)) * D_))[tid];
    const float4 gr = ((const float4*)(x3 + ((size_t)(m + b + 1)) * D_))[tid];
    v.x -= se.x + gr.x; v.y -= se.y + gr.y; v.z -= se.z + gr.z; v.w -= se.w + gr.w;
  }
  float s = v.x + v.y + v.z + v.w;
  float s2 = v.x * v.x + v.y * v.y + v.z * v.z + v.w * v.w;
#pragma unroll
  for (int off = 32; off; off >>= 1) { s += __shfl_down(s, off); s2 += __shfl_down(s2, off); }
  __shared__ float p1[2], p2[2];
  if ((tid & 63) == 0) { p1[tid >> 6] = s; p2[tid >> 6] = s2; }
  __syncthreads();
  const float S = p1[0] + p1[1], S2 = p2[0] + p2[1];
  const float mu = S * (1.0f / 512.0f);
  const float rs = rsqrtf(fmaxf(S2 * (1.0f / 512.0f) - mu * mu, 0.0f) + 1e-5f);
  const float4 gg = ((const float4*)g)[tid], bb = ((const float4*)be)[tid];
  float4 o;
  o.x = (v.x - mu) * rs * gg.x + bb.x;
  o.y = (v.y - mu) * rs * gg.y + bb.y;
  o.z = (v.z - mu) * rs * gg.z + bb.z;
  o.w = (v.w - mu) * rs * gg.w + bb.w;
  ((float4*)(outF + (size_t)m * D_))[tid] = o;
  if (MODE == 0) {
    bf16* ob = outB + (size_t)m * D_ + tid * 4;
    ob[0] = __float2bfloat16(o.x); ob[1] = __float2bfloat16(o.y);
    ob[2] = __float2bfloat16(o.z); ob[3] = __float2bfloat16(o.w);
  }
}

// ---------------- bf16 MFMA GEMM, swizzled LDS + counted-vmcnt pipeline ----------------
// tm = blockIdx.x (FASTEST dispatch index): same-tm blocks (sharing the A row-panel)
// get dispatch ids congruent mod NXCD -> co-locate on one XCD's L2 (A staged as L2 hit).
template <int BM, int BN, int BK, int WM, int WN, int EPI, bool DUAL = false>
__global__ __launch_bounds__(WM * WN * 64, 2) void k_gemm(
    const bf16* __restrict__ A, const bf16* __restrict__ Bw,
    const float* __restrict__ bias, float* outF, bf16* __restrict__ outB,
    const float* resid, const int M, const int N, const int K, int extra,
    const bf16* __restrict__ A2, const bf16* __restrict__ Bw2,
    const float* __restrict__ bias2, float* outF2, int extra2) {
  constexpr int NW = WM * WN;
  constexpr int FM = BM / (WM * 16);
  constexpr int FN = BN / (WN * 16);
  constexpr int RPC = 512 / BK;
  constexpr int LA = (BM / RPC) / NW, LB = (BN / RPC) / NW;
  constexpr int KK = BK / 32;
  constexpr int TLOADS = LA + LB;
  static_assert(LA >= 1 && LB >= 1, "tile too small for staging split");
  static_assert((BM / RPC) % NW == 0 && (BN / RPC) % NW == 0, "staging split");
  if constexpr (DUAL) {
    if (blockIdx.z == 1) { A = A2; Bw = Bw2; bias = bias2; outF = outF2; extra = extra2; }
  }
  __shared__ bf16 lsA[2][BM * BK];
  __shared__ bf16 lsB[2][BN * BK];
  const int tid = threadIdx.x;
  const int w = tid >> 6, lane = tid & 63;
  const int tm = blockIdx.x, tn = blockIdx.y;   // tm fastest -> XCD A-locality
  const int wr = w / WN, wc = w % WN;
  const int r16 = lane & 15, hi = lane >> 4;

  int srowoff, scoloff;
  if constexpr (BK == 64) {
    const int rr = lane >> 3, cs = lane & 7;
    srowoff = rr;
    scoloff = (cs ^ rr) * 8;
  } else {
    const int sr = lane >> 3, cs = lane & 7;
    const int idx = cs ^ (sr & 7);
    srowoff = sr * 2 + (idx >> 2);
    scoloff = (idx & 3) * 8;
  }

  const f32x4 fzero = {0.f, 0.f, 0.f, 0.f};
  f32x4 acc[FM][FN];
#pragma unroll
  for (int i = 0; i < FM; i++)
#pragma unroll
    for (int jj = 0; jj < FN; jj++) acc[i][jj] = fzero;

  const int NT = K / BK;

  auto stage = [&](int kt, int sel) {
#pragma unroll
    for (int q = 0; q < LA; q++) {
      const int g = w * LA + q;
      int m = tm * BM + g * RPC + srowoff;
      if (m > M - 1) m = M - 1;
      m += (m >> 10) * extra;
      gload_lds16(A + (size_t)m * K + (size_t)kt * BK + scoloff, &lsA[sel][g * 512]);
    }
#pragma unroll
    for (int q = 0; q < LB; q++) {
      const int g = w * LB + q;
      const int n = tn * BN + g * RPC + srowoff;
      gload_lds16(Bw + (size_t)n * K + (size_t)kt * BK + scoloff, &lsB[sel][g * 512]);
    }
  };

  auto frag = [&](const bf16* ls, int row, int cc) -> bf16x8 {
    if constexpr (BK == 64) {
      const int g = row >> 3, rr = row & 7;
      return *(const bf16x8*)&ls[g * 512 + rr * 64 + ((cc ^ rr) << 3)];
    } else {
      const int g = row >> 4, rr = row & 15, sr = rr >> 1;
      const int idx = ((rr & 1) << 2) | cc;
      return *(const bf16x8*)&ls[g * 512 + sr * 64 + ((idx ^ (sr & 7)) << 3)];
    }
  };

  stage(0, 0);
  for (int kt = 0; kt < NT; ++kt) {
    const int sel = kt & 1;
    if (kt + 1 < NT) {
      stage(kt + 1, sel ^ 1);
      vm_wait<TLOADS>();
    } else {
      vm_wait<0>();
    }
    __builtin_amdgcn_sched_barrier(0);
    __builtin_amdgcn_s_barrier();
    __builtin_amdgcn_sched_barrier(0);
#pragma unroll
    for (int kk = 0; kk < KK; ++kk) {
      bf16x8 af[FM], bfv[FN];
#pragma unroll
      for (int i = 0; i < FM; i++)
        af[i] = frag(lsA[sel], wr * (FM * 16) + i * 16 + r16, kk * 4 + hi);
#pragma unroll
      for (int jj = 0; jj < FN; jj++)
        bfv[jj] = frag(lsB[sel], wc * (FN * 16) + jj * 16 + r16, kk * 4 + hi);
#pragma unroll
      for (int i = 0; i < FM; i++)
#pragma unroll
        for (int jj = 0; jj < FN; jj++)
          acc[i][jj] = __builtin_amdgcn_mfma_f32_16x16x32_bf16(af[i], bfv[jj], acc[i][jj], 0, 0, 0);
    }
    if (kt + 1 < NT) {
      __builtin_amdgcn_sched_barrier(0);
      __builtin_amdgcn_s_barrier();
      __builtin_amdgcn_sched_barrier(0);
    }
  }

#pragma unroll
  for (int i = 0; i < FM; i++) {
#pragma unroll
    for (int r = 0; r < 4; r++) {
      const int m = tm * BM + wr * (FM * 16) + i * 16 + hi * 4 + r;
      if (m < M) {
#pragma unroll
        for (int jj = 0; jj < FN; jj++) {
          const int n = tn * BN + wc * (FN * 16) + jj * 16 + r16;
          float x = acc[i][jj][r];
          if (bias) x += bias[n];
          const size_t idx = (size_t)m * N + n;
          if (EPI == 0) {
            outF[idx] = x;
          } else if (EPI == 1) {
            outF[idx] = x;
            outB[idx] = __float2bfloat16(x);
          } else if (EPI == 2) {
            outB[idx] = __float2bfloat16(1.0f / (1.0f + __expf(-x)));
          } else {
            outF[idx] = x + resid[idx];
          }
        }
      }
    }
  }
}

// ---------------- workspace layout ----------------
#define MB (size_t)(1u << 20)
static const size_t OFF_A = 0;
static const size_t OFF_C = 32 * MB;
static const size_t OFF_D = 40 * MB;
static const size_t OFF_E = 48 * MB;
static const size_t OFF_F = 54 * MB;
static const size_t OFF_G = 63 * MB;
static const size_t OFF_H = 72 * MB;
static const size_t OFF_J = 88 * MB;
static const size_t OFF_K = 89 * MB;
static const size_t OFF_K2 = 91 * MB;

#define W_IN 0
#define W_OUT 262144
#define W_FF1 524288
#define W_FF2 1572864
#define W_GW 2621440
#define W_SW2 2654208

extern "C" void kernel_launch(void* const* d_in, const int* in_sizes, int n_in, void* d_out, int out_size,
                              void* d_ws, size_t ws_size, hipStream_t stream) {
  (void)in_sizes; (void)n_in; (void)out_size; (void)ws_size;
  const float* res = (const float*)d_in[0];
  const float* level = (const float*)d_in[1];
  const float* gl_z0 = (const float*)d_in[2];
  const float* gl_in_w = (const float*)d_in[3];
  const float* gl_in_b = (const float*)d_in[4];
  const float* gl_sw = (const float*)d_in[5];
  const float* gl_v0 = (const float*)d_in[6];
  const float* gl_out_w = (const float*)d_in[7];
  const float* gl_out_b = (const float*)d_in[8];
  const float* ll_sw = (const float*)d_in[9];
  const float* ll_v0 = (const float*)d_in[10];
  const float* ll_gw = (const float*)d_in[11];
  const float* ll_gb = (const float*)d_in[12];
  const float* ll_sw2 = (const float*)d_in[13];
  const float* ll_sb = (const float*)d_in[14];
  const float* ff_w1 = (const float*)d_in[15];
  const float* ff_w2 = (const float*)d_in[16];
  const float* n1_g = (const float*)d_in[17];
  const float* n1_b = (const float*)d_in[18];
  const float* n2_g = (const float*)d_in[19];
  const float* n2_b = (const float*)d_in[20];

  char* ws = (char*)d_ws;
  float* resT = (float*)(ws + OFF_A);
  float* vbuf = (float*)(ws + OFF_A);
  bf16* hbuf = (bf16*)(ws + OFF_A);
  bf16* res1b = (bf16*)(ws + OFF_C);
  bf16* res2b = (bf16*)(ws + OFF_C);
  bf16* seasb = (bf16*)(ws + OFF_D);
  bf16* wE = (bf16*)(ws + OFF_E);
  bf16* s2b = (bf16*)(ws + OFF_F);
  bf16* grob = (bf16*)(ws + OFF_G);
  float* res2f = (float*)(ws + OFF_H);
  float* comp = (float*)(ws + OFF_J);
  float* gproj = (float*)(ws + OFF_K);
  float* sproj = (float*)(ws + OFF_K2);

  float* o_res = (float*)d_out;
  float* o_level = o_res + 4194304;
  float* o_growth = o_level + 524288;
  float* o_season = o_growth + 4198400;

  k_transpose<<<dim3(16, 32, 8), dim3(32, 8), 0, stream>>>(res, resT);
  k_fft_topk<<<2048, 256, 0, stream>>>(resT, comp);
  k_season<<<dim3(256, 8), 512, 0, stream>>>(comp, res, o_season, res1b, seasb);
  k_cvt_all<<<(CVT_TOTAL / 4 + 255) / 256, 256, 0, stream>>>(gl_in_w, gl_out_w, ff_w1, ff_w2, ll_gw, ll_sw2, wE);
  // v = res1 @ gl_in_w^T + b   (64x128, BK=64, 4 waves; tm-fastest grid)
  k_gemm<64, 128, 64, 2, 2, 0><<<dim3(128, 4), 256, 0, stream>>>(
      res1b, wE + W_IN, gl_in_b, vbuf, nullptr, nullptr, 8192, 512, 512, 0,
      nullptr, nullptr, nullptr, nullptr, 0);
  k_growth_scan2<<<64, 1024, 0, stream>>>(vbuf, gl_z0, gl_sw, gl_v0, s2b);
  // growth = s2 @ gl_out_w^T + b
  k_gemm<64, 128, 64, 2, 2, 1><<<dim3(129, 4), 256, 0, stream>>>(
      s2b, wE + W_OUT, gl_out_b, o_growth, grob, nullptr, 8200, 512, 512, 0,
      nullptr, nullptr, nullptr, nullptr, 0);
  k_ln<0><<<8192, 128, 0, stream>>>(res, o_season, o_growth, n1_g, n1_b, res2f, res2b);
  // FF1: 128x128 BK=32, 4 waves, tm-fastest grid
  k_gemm<128, 128, 32, 2, 2, 2><<<dim3(64, 16), 256, 0, stream>>>(
      res2b, wE + W_FF1, nullptr, nullptr, hbuf, nullptr, 8192, 2048, 512, 0,
      nullptr, nullptr, nullptr, nullptr, 0);
  // FF2: 64x128 BK=64, K=2048
  k_gemm<64, 128, 64, 2, 2, 3><<<dim3(128, 4), 256, 0, stream>>>(
      hbuf, wE + W_FF2, nullptr, res2f, nullptr, res2f, 8192, 512, 2048, 0,
      nullptr, nullptr, nullptr, nullptr, 0);
  k_ln<1><<<8192, 128, 0, stream>>>(res2f, nullptr, nullptr, n2_g, n2_b, o_res, nullptr);
  // gproj & sproj merged: one dual dispatch (z=0: growth@ll_gw; z=1: season@ll_sw2)
  k_gemm<64, 64, 64, 4, 1, 0, true><<<dim3(128, 1, 2), 256, 0, stream>>>(
      grob, wE + W_GW, ll_gb, gproj, nullptr, nullptr, 8192, 64, 512, 1,
      seasb, wE + W_SW2, ll_sb, sproj, 0);
  k_level_scan2<<<8, 1024, 0, stream>>>(level, gproj, sproj, ll_sw, ll_v0, o_level);
}

// Round 15
// 216.414 us; speedup vs baseline: 1.0422x; 1.0166x over previous
//
#include <hip/hip_runtime.h>
#include <hip/hip_bf16.h>
#include <math.h>

#define B_ 8
#define T_ 1024
#define D_ 512
#define PRED 256
#define TP (T_ + PRED)
#define NH 8
#define DH 64
#define DFF 2048
#define CO 64
#define KSEL 8

typedef __hip_bfloat16 bf16;
using bf16x8 = __attribute__((ext_vector_type(8))) short;
using f32x4  = __attribute__((ext_vector_type(4))) float;

__device__ __forceinline__ void gload_lds16(const void* gp, void* lp) {
  __builtin_amdgcn_global_load_lds(
      (const __attribute__((address_space(1))) void*)gp,
      (__attribute__((address_space(3))) void*)lp, 16, 0, 0);
}

// counted vmem wait (N = loads allowed to stay in flight)
template <int N>
__device__ __forceinline__ void vm_wait() {
  if constexpr (N == 0)      asm volatile("s_waitcnt vmcnt(0)" ::: "memory");
  else if constexpr (N == 2) asm volatile("s_waitcnt vmcnt(2)" ::: "memory");
  else if constexpr (N == 4) asm volatile("s_waitcnt vmcnt(4)" ::: "memory");
  else if constexpr (N == 6) asm volatile("s_waitcnt vmcnt(6)" ::: "memory");
  else if constexpr (N == 8) asm volatile("s_waitcnt vmcnt(8)" ::: "memory");
  else static_assert(N == 0, "unsupported vmcnt literal");
}

// ---------------- transpose res (b,T,D) -> resT (b,D,T) ----------------
__global__ __launch_bounds__(256) void k_transpose(const float* __restrict__ in, float* __restrict__ out) {
  __shared__ float tile[32][33];
  const int b = blockIdx.z;
  const int d0 = blockIdx.x * 32, t0 = blockIdx.y * 32;
  const int tx = threadIdx.x, ty = threadIdx.y;
  const float* src = in + ((size_t)b * T_ + t0) * D_ + d0;
#pragma unroll
  for (int i = 0; i < 32; i += 8) tile[ty + i][tx] = src[(size_t)(ty + i) * D_ + tx];
  __syncthreads();
  float* dst = out + ((size_t)b * D_ + d0) * T_ + t0;
#pragma unroll
  for (int i = 0; i < 32; i += 8) dst[(size_t)(ty + i) * T_ + tx] = tile[tx][ty + i];
}

// ---------------- 1024-pt real FFT, 2 series/block, radix-4 Stockham + reg top-8 ----------------
// Stages: r2 (s=1) then r4 (s=2,8,32,128): 5 barriers vs 9. Data ends in bufB.
// Top-k: candidates in registers; per round 1 barrier (parity-buffered partials),
// all threads redundantly compute the winner and poison their own registers.
__global__ __launch_bounds__(256) void k_fft_topk(const float* __restrict__ xt, float* __restrict__ comp) {
  __shared__ float2 bufA[2][512], bufB[2][512];
  __shared__ float2 tw[384];
  __shared__ float wvv[2][2][4];
  __shared__ int wkk[2][2][4];
  __shared__ int selk[2][KSEL];
  float* const mg0 = (float*)&bufA[0][0];
  float* const mg1 = (float*)&bufA[1][0];
  const int j = threadIdx.x;
  const size_t bd0 = (size_t)blockIdx.x * 2;
  {
    const float c = -6.283185307179586f / 512.0f;
    tw[j] = make_float2(__cosf(c * (float)j), __sinf(c * (float)j));
    if (j < 128) tw[256 + j] = make_float2(__cosf(c * (float)(256 + j)), __sinf(c * (float)(256 + j)));
  }
  const float4 u0 = ((const float4*)(xt + bd0 * 1024))[j];
  const float4 u1 = ((const float4*)(xt + (bd0 + 1) * 1024))[j];
  bufA[0][2 * j] = make_float2(u0.x, u0.y); bufA[0][2 * j + 1] = make_float2(u0.z, u0.w);
  bufA[1][2 * j] = make_float2(u1.x, u1.y); bufA[1][2 * j + 1] = make_float2(u1.z, u1.w);
  __syncthreads();
  // stage 0: radix-2, s=1, both series per thread (p=j, m=256)
  {
    const float2 w = tw[j];
#pragma unroll
    for (int sx2 = 0; sx2 < 2; ++sx2) {
      const float2 a = bufA[sx2][j], b = bufA[sx2][j + 256];
      bufB[sx2][2 * j] = make_float2(a.x + b.x, a.y + b.y);
      const float ex = a.x - b.x, ey = a.y - b.y;
      bufB[sx2][2 * j + 1] = make_float2(ex * w.x - ey * w.y, ex * w.y + ey * w.x);
    }
  }
  __syncthreads();
  // stages 1..4: radix-4, thread j -> series j>>7, butterfly idx=j&127
  const int sx = j >> 7, idx = j & 127;
#pragma unroll
  for (int st = 0; st < 4; ++st) {
    const int lg = 1 + 2 * st;          // log2(s): 1,3,5,7 -> s = 2,8,32,128
    const int s = 1 << lg;
    const int p = idx >> lg;
    const int q = idx & (s - 1);
    const float2* src = (st & 1) ? (const float2*)bufA[sx] : (const float2*)bufB[sx];
    float2* dst = (st & 1) ? (float2*)bufB[sx] : (float2*)bufA[sx];
    const float2 x0 = src[idx];
    const float2 x1 = src[idx + 128];
    const float2 x2 = src[idx + 256];
    const float2 x3 = src[idx + 384];
    const float2 e0 = make_float2(x0.x + x2.x, x0.y + x2.y);
    const float2 e1 = make_float2(x0.x - x2.x, x0.y - x2.y);
    const float2 e2 = make_float2(x1.x + x3.x, x1.y + x3.y);
    const float2 e3 = make_float2(x1.x - x3.x, x1.y - x3.y);
    const float2 y0 = make_float2(e0.x + e2.x, e0.y + e2.y);
    const float2 y2 = make_float2(e0.x - e2.x, e0.y - e2.y);
    const float2 y1 = make_float2(e1.x + e3.y, e1.y - e3.x);   // e1 + (-i)e3
    const float2 y3 = make_float2(e1.x - e3.y, e1.y + e3.x);   // e1 + (+i)e3
    const int spi = p << lg;
    const float2 w1 = tw[spi], w2 = tw[2 * spi], w3 = tw[3 * spi];
    const int ob = q + (p << (lg + 2));
    dst[ob] = y0;
    dst[ob + s] = make_float2(y1.x * w1.x - y1.y * w1.y, y1.x * w1.y + y1.y * w1.x);
    dst[ob + 2 * s] = make_float2(y2.x * w2.x - y2.y * w2.y, y2.x * w2.y + y2.y * w2.x);
    dst[ob + 3 * s] = make_float2(y3.x * w3.x - y3.y * w3.y, y3.x * w3.y + y3.y * w3.x);
    __syncthreads();
  }
  // result Z in bufB; bufA dead -> mag2 overlay
#pragma unroll
  for (int u = 0; u < 2; ++u) {
    const int k = (u == 0) ? (j + 1) : (j + 257);
    if (k <= 511) {
#pragma unroll
      for (int s2 = 0; s2 < 2; ++s2) {
        const float2 zk = bufB[s2][k & 511];
        const float2 zm = bufB[s2][(512 - k) & 511];
        const float Ex = 0.5f * (zk.x + zm.x), Ey = 0.5f * (zk.y - zm.y);
        const float Ox = 0.5f * (zk.y + zm.y), Oy = 0.5f * (zm.x - zk.x);
        const float ang = -(6.283185307179586f / 1024.0f) * (float)k;
        const float cs = __cosf(ang), sn = __sinf(ang);
        const float Xr = Ex + cs * Ox - sn * Oy;
        const float Xi = Ey + cs * Oy + sn * Ox;
        ((s2 == 0) ? mg0 : mg1)[k] = Xr * Xr + Xi * Xi;
      }
    }
  }
  __syncthreads();
  // candidates -> registers (bins j and j+256 of both series)
  float a0 = mg0[j], b0v = mg0[j + 256];
  float a1 = mg1[j], b1v = mg1[j + 256];
  if (j == 0) { a0 = -1.0f; a1 = -1.0f; }   // exclude DC bin
  const int lane = j & 63, wvi = j >> 6;
  for (int r = 0; r < KSEL; ++r) {
    const int par = r & 1;
    float bv0 = a0; int bk0 = j;
    if (b0v > bv0) { bv0 = b0v; bk0 = j + 256; }
    float bv1 = a1; int bk1 = j;
    if (b1v > bv1) { bv1 = b1v; bk1 = j + 256; }
#pragma unroll
    for (int off = 32; off; off >>= 1) {
      const float ov0 = __shfl_down(bv0, off); const int ok0 = __shfl_down(bk0, off);
      if (ov0 > bv0 || (ov0 == bv0 && ok0 < bk0)) { bv0 = ov0; bk0 = ok0; }
      const float ov1 = __shfl_down(bv1, off); const int ok1 = __shfl_down(bk1, off);
      if (ov1 > bv1 || (ov1 == bv1 && ok1 < bk1)) { bv1 = ov1; bk1 = ok1; }
    }
    if (lane == 0) {
      wvv[0][par][wvi] = bv0; wkk[0][par][wvi] = bk0;
      wvv[1][par][wvi] = bv1; wkk[1][par][wvi] = bk1;
    }
    __syncthreads();
    // all threads compute identical winners from the 4 partials
    float fv0 = wvv[0][par][0]; int fk0 = wkk[0][par][0];
    float fv1 = wvv[1][par][0]; int fk1 = wkk[1][par][0];
#pragma unroll
    for (int i = 1; i < 4; i++) {
      if (wvv[0][par][i] > fv0 || (wvv[0][par][i] == fv0 && wkk[0][par][i] < fk0)) { fv0 = wvv[0][par][i]; fk0 = wkk[0][par][i]; }
      if (wvv[1][par][i] > fv1 || (wvv[1][par][i] == fv1 && wkk[1][par][i] < fk1)) { fv1 = wvv[1][par][i]; fk1 = wkk[1][par][i]; }
    }
    if (j == 0) { selk[0][r] = fk0; selk[1][r] = fk1; }
    if (fk0 == j) a0 = -2.0f;
    if (fk0 == j + 256) b0v = -2.0f;
    if (fk1 == j) a1 = -2.0f;
    if (fk1 == j + 256) b1v = -2.0f;
  }
  __syncthreads();
  if (j < 2 * KSEL) {
    const int s2 = j >> 3, r = j & 7;
    const int k = selk[s2][r];
    const float2 zk = bufB[s2][k & 511];
    const float2 zm = bufB[s2][(512 - k) & 511];
    const float Ex = 0.5f * (zk.x + zm.x), Ey = 0.5f * (zk.y - zm.y);
    const float Ox = 0.5f * (zk.y + zm.y), Oy = 0.5f * (zm.x - zk.x);
    const float ang = -(6.283185307179586f / 1024.0f) * (float)k;
    const float cs = __cosf(ang), sn = __sinf(ang);
    const float Xr = Ex + cs * Ox - sn * Oy;
    const float Xi = Ey + cs * Oy + sn * Ox;
    float* o = comp + (bd0 + s2) * 24 + r * 3;
    o[0] = 2.0f * sqrtf(Xr * Xr + Xi * Xi) * (1.0f / 1024.0f);
    o[1] = (float)k;
    o[2] = atan2f(Xi, Xr);
  }
}

// ---------------- season synthesis + res1 = res - season ----------------
__global__ __launch_bounds__(512) void k_season(const float* __restrict__ comp, const float* __restrict__ res,
                                                float* __restrict__ season, bf16* __restrict__ res1b,
                                                bf16* __restrict__ seasb) {
  const int d = threadIdx.x;
  const int b = blockIdx.y;
  const int t0 = blockIdx.x * 5;
  float a_[8], kf_[8], ph_[8];
  const float* c = comp + ((size_t)b * 512 + d) * 24;
#pragma unroll
  for (int i = 0; i < 8; i++) { a_[i] = c[3 * i]; kf_[i] = c[3 * i + 1]; ph_[i] = c[3 * i + 2]; }
#pragma unroll
  for (int tt = 0; tt < 5; ++tt) {
    const int t = t0 + tt;
    float acc = 0.0f;
#pragma unroll
    for (int i = 0; i < 8; i++) {
      float fr = kf_[i] * (float)t * (1.0f / 1024.0f);
      fr -= floorf(fr);
      acc += a_[i] * __cosf(fmaf(6.283185307179586f, fr, ph_[i]));
    }
    season[((size_t)b * TP + t) * D_ + d] = acc;
    if (t < T_) {
      const float rr = res[((size_t)b * T_ + t) * D_ + d] - acc;
      res1b[((size_t)b * T_ + t) * D_ + d] = __float2bfloat16(rr);
      seasb[((size_t)b * T_ + t) * D_ + d] = __float2bfloat16(acc);
    }
  }
}

// ---------------- fused f32 -> bf16 for all 6 weight tensors ----------------
#define CVT_TOTAL 2686976
__global__ __launch_bounds__(256) void k_cvt_all(const float* __restrict__ s0, const float* __restrict__ s1,
                                                 const float* __restrict__ s2_, const float* __restrict__ s3,
                                                 const float* __restrict__ s4, const float* __restrict__ s5,
                                                 bf16* __restrict__ dst) {
  const int i = (blockIdx.x * 256 + threadIdx.x) * 4;
  if (i >= CVT_TOTAL) return;
  const float* src;
  int off;
  if (i < 262144)       { src = s0;  off = i; }
  else if (i < 524288)  { src = s1;  off = i - 262144; }
  else if (i < 1572864) { src = s2_; off = i - 524288; }
  else if (i < 2621440) { src = s3;  off = i - 1572864; }
  else if (i < 2654208) { src = s4;  off = i - 2621440; }
  else                  { src = s5;  off = i - 2654208; }
  const float4 v = *(const float4*)(src + off);
  bf16* o = dst + i;
  o[0] = __float2bfloat16(v.x); o[1] = __float2bfloat16(v.y);
  o[2] = __float2bfloat16(v.z); o[3] = __float2bfloat16(v.w);
}

// ---------------- growth exp-smooth blocked scan ----------------
__global__ __launch_bounds__(1024) void k_growth_scan2(const float* __restrict__ v, const float* __restrict__ z0,
                                                       const float* __restrict__ sw, const float* __restrict__ v0,
                                                       bf16* __restrict__ s2) {
  const int b = blockIdx.x >> 3;
  const int col = (blockIdx.x & 7) * 64 + (threadIdx.x & 63);
  const int w = threadIdx.x >> 6;
  const float alpha = 1.0f / (1.0f + expf(-sw[col >> 6]));
  const float om = 1.0f - alpha;
  float a64 = alpha;
#pragma unroll
  for (int i = 0; i < 6; i++) a64 *= a64;
  const float* vp = v + (size_t)b * T_ * D_ + col;
  float vprev = (w == 0) ? z0[col] : vp[(size_t)(64 * w - 1) * D_];
  float sloc = 0.0f;
#pragma unroll 8
  for (int j = 0; j < 64; j++) {
    const float nv = vp[(size_t)(64 * w + j) * D_];
    sloc = alpha * sloc + om * (nv - vprev);
    vprev = nv;
  }
  __shared__ float lb[16][64], lc[16][64];
  lb[w][threadIdx.x & 63] = sloc;
  __syncthreads();
  if (w == 0) {
    float s = v0[col];
#pragma unroll
    for (int k = 0; k < 16; k++) { lc[k][threadIdx.x & 63] = s; s = a64 * s + lb[k][threadIdx.x & 63]; }
  }
  __syncthreads();
  float s = lc[w][threadIdx.x & 63];
  vprev = (w == 0) ? z0[col] : vp[(size_t)(64 * w - 1) * D_];
  bf16* op = s2 + (size_t)b * (T_ + 1) * D_ + col;
  if (w == 0) op[0] = __float2bfloat16(v0[col]);
#pragma unroll 8
  for (int j = 0; j < 64; j++) {
    const float nv = vp[(size_t)(64 * w + j) * D_];
    s = alpha * s + om * (nv - vprev);
    vprev = nv;
    op[(size_t)(64 * w + j + 1) * D_] = __float2bfloat16(s);
  }
}

// ---------------- level exp-smooth blocked scan ----------------
__global__ __launch_bounds__(1024) void k_level_scan2(const float* __restrict__ level, const float* __restrict__ gp,
                                                      const float* __restrict__ sp, const float* __restrict__ sw,
                                                      const float* __restrict__ v0, float* __restrict__ out) {
  const int b = blockIdx.x;
  const int w = threadIdx.x >> 6;
  const int c = threadIdx.x & 63;
  const float alpha = 1.0f / (1.0f + expf(-sw[c]));
  const float om = 1.0f - alpha;
  float a64 = alpha;
#pragma unroll
  for (int i = 0; i < 6; i++) a64 *= a64;
  const size_t base = ((size_t)b * T_ + 64 * w) * CO + c;
  float sloc = 0.0f;
#pragma unroll 8
  for (int j = 0; j < 64; j++) {
    const size_t idx = base + (size_t)j * CO;
    const float u = om * (level[idx] - sp[idx]) + alpha * gp[idx];
    out[idx] = u;
    sloc = alpha * sloc + u;
  }
  __shared__ float lb[16][64], lc[16][64];
  lb[w][c] = sloc;
  __syncthreads();
  if (w == 0) {
    float s = v0[c];
#pragma unroll
    for (int k = 0; k < 16; k++) { lc[k][c] = s; s = a64 * s + lb[k][c]; }
  }
  __syncthreads();
  float s = lc[w][c];
#pragma unroll 8
  for (int j = 0; j < 64; j++) {
    const size_t idx = base + (size_t)j * CO;
    s = alpha * s + out[idx];
    out[idx] = s;
  }
}

// ---------------- layer norm over D=512 ----------------
// MODE 0: x = (float)res1b - growth[:,1:]   (res1b = res - season, bf16)
// MODE 1: x = x1 (f32)
template <int MODE>
__global__ __launch_bounds__(128) void k_ln(const float* __restrict__ x1, const bf16* __restrict__ xb,
                                            const float* __restrict__ x3, const float* __restrict__ g,
                                            const float* __restrict__ be, float* __restrict__ outF,
                                            bf16* __restrict__ outB) {
  const int m = blockIdx.x, tid = threadIdx.x;
  const int b = m >> 10;
  float4 v;
  if (MODE == 0) {
    const ushort4 rb = ((const ushort4*)(xb + (size_t)m * D_))[tid];
    const float4 gr = ((const float4*)(x3 + ((size_t)(m + b + 1)) * D_))[tid];
    v.x = __uint_as_float((unsigned)rb.x << 16) - gr.x;
    v.y = __uint_as_float((unsigned)rb.y << 16) - gr.y;
    v.z = __uint_as_float((unsigned)rb.z << 16) - gr.z;
    v.w = __uint_as_float((unsigned)rb.w << 16) - gr.w;
  } else {
    v = ((const float4*)(x1 + (size_t)m * D_))[tid];
  }
  float s = v.x + v.y + v.z + v.w;
  float s2 = v.x * v.x + v.y * v.y + v.z * v.z + v.w * v.w;
#pragma unroll
  for (int off = 32; off; off >>= 1) { s += __shfl_down(s, off); s2 += __shfl_down(s2, off); }
  __shared__ float p1[2], p2[2];
  if ((tid & 63) == 0) { p1[tid >> 6] = s; p2[tid >> 6] = s2; }
  __syncthreads();
  const float S = p1[0] + p1[1], S2 = p2[0] + p2[1];
  const float mu = S * (1.0f / 512.0f);
  const float rs = rsqrtf(fmaxf(S2 * (1.0f / 512.0f) - mu * mu, 0.0f) + 1e-5f);
  const float4 gg = ((const float4*)g)[tid], bb = ((const float4*)be)[tid];
  float4 o;
  o.x = (v.x - mu) * rs * gg.x + bb.x;
  o.y = (v.y - mu) * rs * gg.y + bb.y;
  o.z = (v.z - mu) * rs * gg.z + bb.z;
  o.w = (v.w - mu) * rs * gg.w + bb.w;
  ((float4*)(outF + (size_t)m * D_))[tid] = o;
  if (MODE == 0) {
    bf16* ob = outB + (size_t)m * D_ + tid * 4;
    ob[0] = __float2bfloat16(o.x); ob[1] = __float2bfloat16(o.y);
    ob[2] = __float2bfloat16(o.z); ob[3] = __float2bfloat16(o.w);
  }
}

// ---------------- bf16 MFMA GEMM, swizzled LDS + counted-vmcnt pipeline ----------------
// tm = blockIdx.x (FASTEST dispatch index): same-tm blocks (sharing the A row-panel)
// get dispatch ids congruent mod NXCD -> co-locate on one XCD's L2 (A staged as L2 hit).
template <int BM, int BN, int BK, int WM, int WN, int EPI, bool DUAL = false>
__global__ __launch_bounds__(WM * WN * 64, 2) void k_gemm(
    const bf16* __restrict__ A, const bf16* __restrict__ Bw,
    const float* __restrict__ bias, float* outF, bf16* __restrict__ outB,
    const float* resid, const int M, const int N, const int K, int extra,
    const bf16* __restrict__ A2, const bf16* __restrict__ Bw2,
    const float* __restrict__ bias2, float* outF2, int extra2) {
  constexpr int NW = WM * WN;
  constexpr int FM = BM / (WM * 16);
  constexpr int FN = BN / (WN * 16);
  constexpr int RPC = 512 / BK;
  constexpr int LA = (BM / RPC) / NW, LB = (BN / RPC) / NW;
  constexpr int KK = BK / 32;
  constexpr int TLOADS = LA + LB;
  static_assert(LA >= 1 && LB >= 1, "tile too small for staging split");
  static_assert((BM / RPC) % NW == 0 && (BN / RPC) % NW == 0, "staging split");
  if constexpr (DUAL) {
    if (blockIdx.z == 1) { A = A2; Bw = Bw2; bias = bias2; outF = outF2; extra = extra2; }
  }
  __shared__ bf16 lsA[2][BM * BK];
  __shared__ bf16 lsB[2][BN * BK];
  const int tid = threadIdx.x;
  const int w = tid >> 6, lane = tid & 63;
  const int tm = blockIdx.x, tn = blockIdx.y;   // tm fastest -> XCD A-locality
  const int wr = w / WN, wc = w % WN;
  const int r16 = lane & 15, hi = lane >> 4;

  int srowoff, scoloff;
  if constexpr (BK == 64) {
    const int rr = lane >> 3, cs = lane & 7;
    srowoff = rr;
    scoloff = (cs ^ rr) * 8;
  } else {
    const int sr = lane >> 3, cs = lane & 7;
    const int idx = cs ^ (sr & 7);
    srowoff = sr * 2 + (idx >> 2);
    scoloff = (idx & 3) * 8;
  }

  const f32x4 fzero = {0.f, 0.f, 0.f, 0.f};
  f32x4 acc[FM][FN];
#pragma unroll
  for (int i = 0; i < FM; i++)
#pragma unroll
    for (int jj = 0; jj < FN; jj++) acc[i][jj] = fzero;

  const int NT = K / BK;

  auto stage = [&](int kt, int sel) {
#pragma unroll
    for (int q = 0; q < LA; q++) {
      const int g = w * LA + q;
      int m = tm * BM + g * RPC + srowoff;
      if (m > M - 1) m = M - 1;
      m += (m >> 10) * extra;
      gload_lds16(A + (size_t)m * K + (size_t)kt * BK + scoloff, &lsA[sel][g * 512]);
    }
#pragma unroll
    for (int q = 0; q < LB; q++) {
      const int g = w * LB + q;
      const int n = tn * BN + g * RPC + srowoff;
      gload_lds16(Bw + (size_t)n * K + (size_t)kt * BK + scoloff, &lsB[sel][g * 512]);
    }
  };

  auto frag = [&](const bf16* ls, int row, int cc) -> bf16x8 {
    if constexpr (BK == 64) {
      const int g = row >> 3, rr = row & 7;
      return *(const bf16x8*)&ls[g * 512 + rr * 64 + ((cc ^ rr) << 3)];
    } else {
      const int g = row >> 4, rr = row & 15, sr = rr >> 1;
      const int idx = ((rr & 1) << 2) | cc;
      return *(const bf16x8*)&ls[g * 512 + sr * 64 + ((idx ^ (sr & 7)) << 3)];
    }
  };

  stage(0, 0);
  for (int kt = 0; kt < NT; ++kt) {
    const int sel = kt & 1;
    if (kt + 1 < NT) {
      stage(kt + 1, sel ^ 1);
      vm_wait<TLOADS>();
    } else {
      vm_wait<0>();
    }
    __builtin_amdgcn_sched_barrier(0);
    __builtin_amdgcn_s_barrier();
    __builtin_amdgcn_sched_barrier(0);
#pragma unroll
    for (int kk = 0; kk < KK; ++kk) {
      bf16x8 af[FM], bfv[FN];
#pragma unroll
      for (int i = 0; i < FM; i++)
        af[i] = frag(lsA[sel], wr * (FM * 16) + i * 16 + r16, kk * 4 + hi);
#pragma unroll
      for (int jj = 0; jj < FN; jj++)
        bfv[jj] = frag(lsB[sel], wc * (FN * 16) + jj * 16 + r16, kk * 4 + hi);
#pragma unroll
      for (int i = 0; i < FM; i++)
#pragma unroll
        for (int jj = 0; jj < FN; jj++)
          acc[i][jj] = __builtin_amdgcn_mfma_f32_16x16x32_bf16(af[i], bfv[jj], acc[i][jj], 0, 0, 0);
    }
    if (kt + 1 < NT) {
      __builtin_amdgcn_sched_barrier(0);
      __builtin_amdgcn_s_barrier();
      __builtin_amdgcn_sched_barrier(0);
    }
  }

#pragma unroll
  for (int i = 0; i < FM; i++) {
#pragma unroll
    for (int r = 0; r < 4; r++) {
      const int m = tm * BM + wr * (FM * 16) + i * 16 + hi * 4 + r;
      if (m < M) {
#pragma unroll
        for (int jj = 0; jj < FN; jj++) {
          const int n = tn * BN + wc * (FN * 16) + jj * 16 + r16;
          float x = acc[i][jj][r];
          if (bias) x += bias[n];
          const size_t idx = (size_t)m * N + n;
          if (EPI == 0) {
            outF[idx] = x;
          } else if (EPI == 1) {
            outF[idx] = x;
            outB[idx] = __float2bfloat16(x);
          } else if (EPI == 2) {
            outB[idx] = __float2bfloat16(1.0f / (1.0f + __expf(-x)));
          } else {
            outF[idx] = x + resid[idx];
          }
        }
      }
    }
  }
}

// ---------------- workspace layout ----------------
#define MB (size_t)(1u << 20)
static const size_t OFF_A = 0;
static const size_t OFF_C = 32 * MB;
static const size_t OFF_D = 40 * MB;
static const size_t OFF_E = 48 * MB;
static const size_t OFF_F = 54 * MB;
static const size_t OFF_G = 63 * MB;
static const size_t OFF_H = 72 * MB;
static const size_t OFF_J = 88 * MB;
static const size_t OFF_K = 89 * MB;
static const size_t OFF_K2 = 91 * MB;

#define W_IN 0
#define W_OUT 262144
#define W_FF1 524288
#define W_FF2 1572864
#define W_GW 2621440
#define W_SW2 2654208

extern "C" void kernel_launch(void* const* d_in, const int* in_sizes, int n_in, void* d_out, int out_size,
                              void* d_ws, size_t ws_size, hipStream_t stream) {
  (void)in_sizes; (void)n_in; (void)out_size; (void)ws_size;
  const float* res = (const float*)d_in[0];
  const float* level = (const float*)d_in[1];
  const float* gl_z0 = (const float*)d_in[2];
  const float* gl_in_w = (const float*)d_in[3];
  const float* gl_in_b = (const float*)d_in[4];
  const float* gl_sw = (const float*)d_in[5];
  const float* gl_v0 = (const float*)d_in[6];
  const float* gl_out_w = (const float*)d_in[7];
  const float* gl_out_b = (const float*)d_in[8];
  const float* ll_sw = (const float*)d_in[9];
  const float* ll_v0 = (const float*)d_in[10];
  const float* ll_gw = (const float*)d_in[11];
  const float* ll_gb = (const float*)d_in[12];
  const float* ll_sw2 = (const float*)d_in[13];
  const float* ll_sb = (const float*)d_in[14];
  const float* ff_w1 = (const float*)d_in[15];
  const float* ff_w2 = (const float*)d_in[16];
  const float* n1_g = (const float*)d_in[17];
  const float* n1_b = (const float*)d_in[18];
  const float* n2_g = (const float*)d_in[19];
  const float* n2_b = (const float*)d_in[20];

  char* ws = (char*)d_ws;
  float* resT = (float*)(ws + OFF_A);
  float* vbuf = (float*)(ws + OFF_A);
  bf16* hbuf = (bf16*)(ws + OFF_A);
  bf16* res1b = (bf16*)(ws + OFF_C);
  bf16* res2b = (bf16*)(ws + OFF_C);
  bf16* seasb = (bf16*)(ws + OFF_D);
  bf16* wE = (bf16*)(ws + OFF_E);
  bf16* s2b = (bf16*)(ws + OFF_F);
  bf16* grob = (bf16*)(ws + OFF_G);
  float* res2f = (float*)(ws + OFF_H);
  float* comp = (float*)(ws + OFF_J);
  float* gproj = (float*)(ws + OFF_K);
  float* sproj = (float*)(ws + OFF_K2);

  float* o_res = (float*)d_out;
  float* o_level = o_res + 4194304;
  float* o_growth = o_level + 524288;
  float* o_season = o_growth + 4198400;

  k_transpose<<<dim3(16, 32, 8), dim3(32, 8), 0, stream>>>(res, resT);
  k_fft_topk<<<2048, 256, 0, stream>>>(resT, comp);
  k_season<<<dim3(256, 8), 512, 0, stream>>>(comp, res, o_season, res1b, seasb);
  k_cvt_all<<<(CVT_TOTAL / 4 + 255) / 256, 256, 0, stream>>>(gl_in_w, gl_out_w, ff_w1, ff_w2, ll_gw, ll_sw2, wE);
  // v = res1 @ gl_in_w^T + b   (64x128, BK=64, 4 waves; tm-fastest grid)
  k_gemm<64, 128, 64, 2, 2, 0><<<dim3(128, 4), 256, 0, stream>>>(
      res1b, wE + W_IN, gl_in_b, vbuf, nullptr, nullptr, 8192, 512, 512, 0,
      nullptr, nullptr, nullptr, nullptr, 0);
  k_growth_scan2<<<64, 1024, 0, stream>>>(vbuf, gl_z0, gl_sw, gl_v0, s2b);
  // growth = s2 @ gl_out_w^T + b
  k_gemm<64, 128, 64, 2, 2, 1><<<dim3(129, 4), 256, 0, stream>>>(
      s2b, wE + W_OUT, gl_out_b, o_growth, grob, nullptr, 8200, 512, 512, 0,
      nullptr, nullptr, nullptr, nullptr, 0);
  // LN1 from res1b (bf16) - growth[:,1:]
  k_ln<0><<<8192, 128, 0, stream>>>(nullptr, res1b, o_growth, n1_g, n1_b, res2f, res2b);
  // FF1: 128x128 BK=32, 4 waves, tm-fastest grid
  k_gemm<128, 128, 32, 2, 2, 2><<<dim3(64, 16), 256, 0, stream>>>(
      res2b, wE + W_FF1, nullptr, nullptr, hbuf, nullptr, 8192, 2048, 512, 0,
      nullptr, nullptr, nullptr, nullptr, 0);
  // FF2: 64x128 BK=64, K=2048
  k_gemm<64, 128, 64, 2, 2, 3><<<dim3(128, 4), 256, 0, stream>>>(
      hbuf, wE + W_FF2, nullptr, res2f, nullptr, res2f, 8192, 512, 2048, 0,
      nullptr, nullptr, nullptr, nullptr, 0);
  k_ln<1><<<8192, 128, 0, stream>>>(res2f, nullptr, nullptr, n2_g, n2_b, o_res, nullptr);
  // gproj & sproj merged: one dual dispatch (z=0: growth@ll_gw; z=1: season@ll_sw2)
  k_gemm<64, 64, 64, 4, 1, 0, true><<<dim3(128, 1, 2), 256, 0, stream>>>(
      grob, wE + W_GW, ll_gb, gproj, nullptr, nullptr, 8192, 64, 512, 1,
      seasb, wE + W_SW2, ll_sb, sproj, 0);
  k_level_scan2<<<8, 1024, 0, stream>>>(level, gproj, sproj, ll_sw, ll_v0, o_level);
}

// Round 16
// 215.152 us; speedup vs baseline: 1.0483x; 1.0059x over previous
//
#include <hip/hip_runtime.h>
#include <hip/hip_bf16.h>
#include <math.h>

#define B_ 8
#define T_ 1024
#define D_ 512
#define PRED 256
#define TP (T_ + PRED)
#define NH 8
#define DH 64
#define DFF 2048
#define CO 64
#define KSEL 8

typedef __hip_bfloat16 bf16;
using bf16x8 = __attribute__((ext_vector_type(8))) short;
using f32x4  = __attribute__((ext_vector_type(4))) float;

__device__ __forceinline__ void gload_lds16(const void* gp, void* lp) {
  __builtin_amdgcn_global_load_lds(
      (const __attribute__((address_space(1))) void*)gp,
      (__attribute__((address_space(3))) void*)lp, 16, 0, 0);
}

template <int N>
__device__ __forceinline__ void vm_wait() {
  if constexpr (N == 0)      asm volatile("s_waitcnt vmcnt(0)" ::: "memory");
  else if constexpr (N == 2) asm volatile("s_waitcnt vmcnt(2)" ::: "memory");
  else if constexpr (N == 4) asm volatile("s_waitcnt vmcnt(4)" ::: "memory");
  else if constexpr (N == 6) asm volatile("s_waitcnt vmcnt(6)" ::: "memory");
  else if constexpr (N == 8) asm volatile("s_waitcnt vmcnt(8)" ::: "memory");
  else static_assert(N == 0, "unsupported vmcnt literal");
}

// ---------------- transpose res (b,T,D) -> resT (b,D,T) ----------------
__global__ __launch_bounds__(256) void k_transpose(const float* __restrict__ in, float* __restrict__ out) {
  __shared__ float tile[32][33];
  const int b = blockIdx.z;
  const int d0 = blockIdx.x * 32, t0 = blockIdx.y * 32;
  const int tx = threadIdx.x, ty = threadIdx.y;
  const float* src = in + ((size_t)b * T_ + t0) * D_ + d0;
#pragma unroll
  for (int i = 0; i < 32; i += 8) tile[ty + i][tx] = src[(size_t)(ty + i) * D_ + tx];
  __syncthreads();
  float* dst = out + ((size_t)b * D_ + d0) * T_ + t0;
#pragma unroll
  for (int i = 0; i < 32; i += 8) dst[(size_t)(ty + i) * T_ + tx] = tile[tx][ty + i];
}

// ---------------- 1024-pt real FFT, 2 series/block, radix-4 Stockham + reg top-8 ----------------
__global__ __launch_bounds__(256) void k_fft_topk(const float* __restrict__ xt, float* __restrict__ comp) {
  __shared__ float2 bufA[2][512], bufB[2][512];
  __shared__ float2 tw[384];
  __shared__ float wvv[2][2][4];
  __shared__ int wkk[2][2][4];
  __shared__ int selk[2][KSEL];
  float* const mg0 = (float*)&bufA[0][0];
  float* const mg1 = (float*)&bufA[1][0];
  const int j = threadIdx.x;
  const size_t bd0 = (size_t)blockIdx.x * 2;
  {
    const float c = -6.283185307179586f / 512.0f;
    tw[j] = make_float2(__cosf(c * (float)j), __sinf(c * (float)j));
    if (j < 128) tw[256 + j] = make_float2(__cosf(c * (float)(256 + j)), __sinf(c * (float)(256 + j)));
  }
  const float4 u0 = ((const float4*)(xt + bd0 * 1024))[j];
  const float4 u1 = ((const float4*)(xt + (bd0 + 1) * 1024))[j];
  bufA[0][2 * j] = make_float2(u0.x, u0.y); bufA[0][2 * j + 1] = make_float2(u0.z, u0.w);
  bufA[1][2 * j] = make_float2(u1.x, u1.y); bufA[1][2 * j + 1] = make_float2(u1.z, u1.w);
  __syncthreads();
  {
    const float2 w = tw[j];
#pragma unroll
    for (int sx2 = 0; sx2 < 2; ++sx2) {
      const float2 a = bufA[sx2][j], b = bufA[sx2][j + 256];
      bufB[sx2][2 * j] = make_float2(a.x + b.x, a.y + b.y);
      const float ex = a.x - b.x, ey = a.y - b.y;
      bufB[sx2][2 * j + 1] = make_float2(ex * w.x - ey * w.y, ex * w.y + ey * w.x);
    }
  }
  __syncthreads();
  const int sx = j >> 7, idx = j & 127;
#pragma unroll
  for (int st = 0; st < 4; ++st) {
    const int lg = 1 + 2 * st;
    const int s = 1 << lg;
    const int p = idx >> lg;
    const int q = idx & (s - 1);
    const float2* src = (st & 1) ? (const float2*)bufA[sx] : (const float2*)bufB[sx];
    float2* dst = (st & 1) ? (float2*)bufB[sx] : (float2*)bufA[sx];
    const float2 x0 = src[idx];
    const float2 x1 = src[idx + 128];
    const float2 x2 = src[idx + 256];
    const float2 x3 = src[idx + 384];
    const float2 e0 = make_float2(x0.x + x2.x, x0.y + x2.y);
    const float2 e1 = make_float2(x0.x - x2.x, x0.y - x2.y);
    const float2 e2 = make_float2(x1.x + x3.x, x1.y + x3.y);
    const float2 e3 = make_float2(x1.x - x3.x, x1.y - x3.y);
    const float2 y0 = make_float2(e0.x + e2.x, e0.y + e2.y);
    const float2 y2 = make_float2(e0.x - e2.x, e0.y - e2.y);
    const float2 y1 = make_float2(e1.x + e3.y, e1.y - e3.x);
    const float2 y3 = make_float2(e1.x - e3.y, e1.y + e3.x);
    const int spi = p << lg;
    const float2 w1 = tw[spi], w2 = tw[2 * spi], w3 = tw[3 * spi];
    const int ob = q + (p << (lg + 2));
    dst[ob] = y0;
    dst[ob + s] = make_float2(y1.x * w1.x - y1.y * w1.y, y1.x * w1.y + y1.y * w1.x);
    dst[ob + 2 * s] = make_float2(y2.x * w2.x - y2.y * w2.y, y2.x * w2.y + y2.y * w2.x);
    dst[ob + 3 * s] = make_float2(y3.x * w3.x - y3.y * w3.y, y3.x * w3.y + y3.y * w3.x);
    __syncthreads();
  }
#pragma unroll
  for (int u = 0; u < 2; ++u) {
    const int k = (u == 0) ? (j + 1) : (j + 257);
    if (k <= 511) {
#pragma unroll
      for (int s2 = 0; s2 < 2; ++s2) {
        const float2 zk = bufB[s2][k & 511];
        const float2 zm = bufB[s2][(512 - k) & 511];
        const float Ex = 0.5f * (zk.x + zm.x), Ey = 0.5f * (zk.y - zm.y);
        const float Ox = 0.5f * (zk.y + zm.y), Oy = 0.5f * (zm.x - zk.x);
        const float ang = -(6.283185307179586f / 1024.0f) * (float)k;
        const float cs = __cosf(ang), sn = __sinf(ang);
        const float Xr = Ex + cs * Ox - sn * Oy;
        const float Xi = Ey + cs * Oy + sn * Ox;
        ((s2 == 0) ? mg0 : mg1)[k] = Xr * Xr + Xi * Xi;
      }
    }
  }
  __syncthreads();
  float a0 = mg0[j], b0v = mg0[j + 256];
  float a1 = mg1[j], b1v = mg1[j + 256];
  if (j == 0) { a0 = -1.0f; a1 = -1.0f; }
  const int lane = j & 63, wvi = j >> 6;
  for (int r = 0; r < KSEL; ++r) {
    const int par = r & 1;
    float bv0 = a0; int bk0 = j;
    if (b0v > bv0) { bv0 = b0v; bk0 = j + 256; }
    float bv1 = a1; int bk1 = j;
    if (b1v > bv1) { bv1 = b1v; bk1 = j + 256; }
#pragma unroll
    for (int off = 32; off; off >>= 1) {
      const float ov0 = __shfl_down(bv0, off); const int ok0 = __shfl_down(bk0, off);
      if (ov0 > bv0 || (ov0 == bv0 && ok0 < bk0)) { bv0 = ov0; bk0 = ok0; }
      const float ov1 = __shfl_down(bv1, off); const int ok1 = __shfl_down(bk1, off);
      if (ov1 > bv1 || (ov1 == bv1 && ok1 < bk1)) { bv1 = ov1; bk1 = ok1; }
    }
    if (lane == 0) {
      wvv[0][par][wvi] = bv0; wkk[0][par][wvi] = bk0;
      wvv[1][par][wvi] = bv1; wkk[1][par][wvi] = bk1;
    }
    __syncthreads();
    float fv0 = wvv[0][par][0]; int fk0 = wkk[0][par][0];
    float fv1 = wvv[1][par][0]; int fk1 = wkk[1][par][0];
#pragma unroll
    for (int i = 1; i < 4; i++) {
      if (wvv[0][par][i] > fv0 || (wvv[0][par][i] == fv0 && wkk[0][par][i] < fk0)) { fv0 = wvv[0][par][i]; fk0 = wkk[0][par][i]; }
      if (wvv[1][par][i] > fv1 || (wvv[1][par][i] == fv1 && wkk[1][par][i] < fk1)) { fv1 = wvv[1][par][i]; fk1 = wkk[1][par][i]; }
    }
    if (j == 0) { selk[0][r] = fk0; selk[1][r] = fk1; }
    if (fk0 == j) a0 = -2.0f;
    if (fk0 == j + 256) b0v = -2.0f;
    if (fk1 == j) a1 = -2.0f;
    if (fk1 == j + 256) b1v = -2.0f;
  }
  __syncthreads();
  if (j < 2 * KSEL) {
    const int s2 = j >> 3, r = j & 7;
    const int k = selk[s2][r];
    const float2 zk = bufB[s2][k & 511];
    const float2 zm = bufB[s2][(512 - k) & 511];
    const float Ex = 0.5f * (zk.x + zm.x), Ey = 0.5f * (zk.y - zm.y);
    const float Ox = 0.5f * (zk.y + zm.y), Oy = 0.5f * (zm.x - zk.x);
    const float ang = -(6.283185307179586f / 1024.0f) * (float)k;
    const float cs = __cosf(ang), sn = __sinf(ang);
    const float Xr = Ex + cs * Ox - sn * Oy;
    const float Xi = Ey + cs * Oy + sn * Ox;
    float* o = comp + (bd0 + s2) * 24 + r * 3;
    o[0] = 2.0f * sqrtf(Xr * Xr + Xi * Xi) * (1.0f / 1024.0f);
    o[1] = (float)k;
    o[2] = atan2f(Xi, Xr);
  }
}

// ---------------- season synthesis + res1 = res - season ----------------
// seasC: bf16 season written into combined A' buffer, physical row b*1025+t, cols 512..1023 (stride 1024)
__global__ __launch_bounds__(512) void k_season(const float* __restrict__ comp, const float* __restrict__ res,
                                                float* __restrict__ season, bf16* __restrict__ res1b,
                                                bf16* __restrict__ seasC) {
  const int d = threadIdx.x;
  const int b = blockIdx.y;
  const int t0 = blockIdx.x * 5;
  float a_[8], kf_[8], ph_[8];
  const float* c = comp + ((size_t)b * 512 + d) * 24;
#pragma unroll
  for (int i = 0; i < 8; i++) { a_[i] = c[3 * i]; kf_[i] = c[3 * i + 1]; ph_[i] = c[3 * i + 2]; }
#pragma unroll
  for (int tt = 0; tt < 5; ++tt) {
    const int t = t0 + tt;
    float acc = 0.0f;
#pragma unroll
    for (int i = 0; i < 8; i++) {
      float fr = kf_[i] * (float)t * (1.0f / 1024.0f);
      fr -= floorf(fr);
      acc += a_[i] * __cosf(fmaf(6.283185307179586f, fr, ph_[i]));
    }
    season[((size_t)b * TP + t) * D_ + d] = acc;
    if (t < T_) {
      const float rr = res[((size_t)b * T_ + t) * D_ + d] - acc;
      res1b[((size_t)b * T_ + t) * D_ + d] = __float2bfloat16(rr);
      seasC[((size_t)b * 1025 + t) * 1024 + 512 + d] = __float2bfloat16(acc);
    }
  }
}

// ---------------- fused f32 -> bf16 weights; last two regions fused+scaled for level layer ----------------
// W'[c] = [ alpha_c * ll_gw[c,:] | -om_c * ll_sw2[c,:] ]  (row stride 1024), alpha=sigmoid(ll_sw)
#define CVT_TOTAL 2686976
__global__ __launch_bounds__(256) void k_cvt_all(const float* __restrict__ s0, const float* __restrict__ s1,
                                                 const float* __restrict__ s2_, const float* __restrict__ s3,
                                                 const float* __restrict__ s4, const float* __restrict__ s5,
                                                 const float* __restrict__ llsw, bf16* __restrict__ dst) {
  const int i = (blockIdx.x * 256 + threadIdx.x) * 4;
  if (i >= CVT_TOTAL) return;
  const float* src;
  int off;
  float scale = 1.0f;
  int di = i;
  if (i < 262144)       { src = s0;  off = i; }
  else if (i < 524288)  { src = s1;  off = i - 262144; }
  else if (i < 1572864) { src = s2_; off = i - 524288; }
  else if (i < 2621440) { src = s3;  off = i - 1572864; }
  else if (i < 2654208) {
    src = s4;  off = i - 2621440;
    const int c = off >> 9, k = off & 511;
    scale = 1.0f / (1.0f + __expf(-llsw[c]));          // alpha
    di = 2621440 + c * 1024 + k;
  } else {
    src = s5;  off = i - 2654208;
    const int c = off >> 9, k = off & 511;
    const float alpha = 1.0f / (1.0f + __expf(-llsw[c]));
    scale = -(1.0f - alpha);                            // -om
    di = 2621440 + c * 1024 + 512 + k;
  }
  const float4 v = *(const float4*)(src + off);
  bf16* o = dst + di;
  o[0] = __float2bfloat16(v.x * scale); o[1] = __float2bfloat16(v.y * scale);
  o[2] = __float2bfloat16(v.z * scale); o[3] = __float2bfloat16(v.w * scale);
}

// ---------------- growth exp-smooth blocked scan ----------------
__global__ __launch_bounds__(1024) void k_growth_scan2(const float* __restrict__ v, const float* __restrict__ z0,
                                                       const float* __restrict__ sw, const float* __restrict__ v0,
                                                       bf16* __restrict__ s2) {
  const int b = blockIdx.x >> 3;
  const int col = (blockIdx.x & 7) * 64 + (threadIdx.x & 63);
  const int w = threadIdx.x >> 6;
  const float alpha = 1.0f / (1.0f + expf(-sw[col >> 6]));
  const float om = 1.0f - alpha;
  float a64 = alpha;
#pragma unroll
  for (int i = 0; i < 6; i++) a64 *= a64;
  const float* vp = v + (size_t)b * T_ * D_ + col;
  float vprev = (w == 0) ? z0[col] : vp[(size_t)(64 * w - 1) * D_];
  float sloc = 0.0f;
#pragma unroll 8
  for (int j = 0; j < 64; j++) {
    const float nv = vp[(size_t)(64 * w + j) * D_];
    sloc = alpha * sloc + om * (nv - vprev);
    vprev = nv;
  }
  __shared__ float lb[16][64], lc[16][64];
  lb[w][threadIdx.x & 63] = sloc;
  __syncthreads();
  if (w == 0) {
    float s = v0[col];
#pragma unroll
    for (int k = 0; k < 16; k++) { lc[k][threadIdx.x & 63] = s; s = a64 * s + lb[k][threadIdx.x & 63]; }
  }
  __syncthreads();
  float s = lc[w][threadIdx.x & 63];
  vprev = (w == 0) ? z0[col] : vp[(size_t)(64 * w - 1) * D_];
  bf16* op = s2 + (size_t)b * (T_ + 1) * D_ + col;
  if (w == 0) op[0] = __float2bfloat16(v0[col]);
#pragma unroll 8
  for (int j = 0; j < 64; j++) {
    const float nv = vp[(size_t)(64 * w + j) * D_];
    s = alpha * s + om * (nv - vprev);
    vprev = nv;
    op[(size_t)(64 * w + j + 1) * D_] = __float2bfloat16(s);
  }
}

// ---------------- level exp-smooth blocked scan: u precomputed (ubuf), scan -> out ----------------
__global__ __launch_bounds__(1024) void k_level_scan2(const float* __restrict__ ubuf, const float* __restrict__ sw,
                                                      const float* __restrict__ v0, float* __restrict__ out) {
  const int b = blockIdx.x;
  const int w = threadIdx.x >> 6;
  const int c = threadIdx.x & 63;
  const float alpha = 1.0f / (1.0f + expf(-sw[c]));
  float a64 = alpha;
#pragma unroll
  for (int i = 0; i < 6; i++) a64 *= a64;
  const size_t base = ((size_t)b * T_ + 64 * w) * CO + c;
  float sloc = 0.0f;
#pragma unroll 8
  for (int j = 0; j < 64; j++) sloc = alpha * sloc + ubuf[base + (size_t)j * CO];
  __shared__ float lb[16][64], lc[16][64];
  lb[w][c] = sloc;
  __syncthreads();
  if (w == 0) {
    float s = v0[c];
#pragma unroll
    for (int k = 0; k < 16; k++) { lc[k][c] = s; s = a64 * s + lb[k][c]; }
  }
  __syncthreads();
  float s = lc[w][c];
#pragma unroll 8
  for (int j = 0; j < 64; j++) {
    const size_t idx = base + (size_t)j * CO;
    s = alpha * s + ubuf[idx];
    out[idx] = s;
  }
}

// ---------------- layer norm over D=512 ----------------
// MODE 0: x = (float)res1b - (float)grobC[phys(m)+1]   (bf16 inputs, grobC stride 1024)
// MODE 1: x = x1 (f32)
template <int MODE>
__global__ __launch_bounds__(128) void k_ln(const float* __restrict__ x1, const bf16* __restrict__ xb,
                                            const bf16* __restrict__ x3, const float* __restrict__ g,
                                            const float* __restrict__ be, float* __restrict__ outF,
                                            bf16* __restrict__ outB) {
  const int m = blockIdx.x, tid = threadIdx.x;
  const int b = m >> 10;
  float4 v;
  if (MODE == 0) {
    const ushort4 rb = ((const ushort4*)(xb + (size_t)m * D_))[tid];
    const ushort4 gr = ((const ushort4*)(x3 + ((size_t)(m + b + 1)) * 1024))[tid];
    v.x = __uint_as_float((unsigned)rb.x << 16) - __uint_as_float((unsigned)gr.x << 16);
    v.y = __uint_as_float((unsigned)rb.y << 16) - __uint_as_float((unsigned)gr.y << 16);
    v.z = __uint_as_float((unsigned)rb.z << 16) - __uint_as_float((unsigned)gr.z << 16);
    v.w = __uint_as_float((unsigned)rb.w << 16) - __uint_as_float((unsigned)gr.w << 16);
  } else {
    v = ((const float4*)(x1 + (size_t)m * D_))[tid];
  }
  float s = v.x + v.y + v.z + v.w;
  float s2 = v.x * v.x + v.y * v.y + v.z * v.z + v.w * v.w;
#pragma unroll
  for (int off = 32; off; off >>= 1) { s += __shfl_down(s, off); s2 += __shfl_down(s2, off); }
  __shared__ float p1[2], p2[2];
  if ((tid & 63) == 0) { p1[tid >> 6] = s; p2[tid >> 6] = s2; }
  __syncthreads();
  const float S = p1[0] + p1[1], S2 = p2[0] + p2[1];
  const float mu = S * (1.0f / 512.0f);
  const float rs = rsqrtf(fmaxf(S2 * (1.0f / 512.0f) - mu * mu, 0.0f) + 1e-5f);
  const float4 gg = ((const float4*)g)[tid], bb = ((const float4*)be)[tid];
  float4 o;
  o.x = (v.x - mu) * rs * gg.x + bb.x;
  o.y = (v.y - mu) * rs * gg.y + bb.y;
  o.z = (v.z - mu) * rs * gg.z + bb.z;
  o.w = (v.w - mu) * rs * gg.w + bb.w;
  ((float4*)(outF + (size_t)m * D_))[tid] = o;
  if (MODE == 0) {
    bf16* ob = outB + (size_t)m * D_ + tid * 4;
    ob[0] = __float2bfloat16(o.x); ob[1] = __float2bfloat16(o.y);
    ob[2] = __float2bfloat16(o.z); ob[3] = __float2bfloat16(o.w);
  }
}

// ---------------- bf16 MFMA GEMM, swizzled LDS + counted-vmcnt pipeline ----------------
// tm = blockIdx.x (FASTEST): same-A-panel blocks co-locate per XCD (L2 A-hits).
// EPI: 0 bias+f32; 1 bias+f32+bf16(stride obst); 2 sigmoid->bf16(stride obst);
//      3 f32 += resid; 4 level-u: out = x + a*gb[n] - om*sb[n] + om*lvl[idx], a=sigmoid(sw4[n])
template <int BM, int BN, int BK, int WM, int WN, int EPI>
__global__ __launch_bounds__(WM * WN * 64, 2) void k_gemm(
    const bf16* __restrict__ A, const bf16* __restrict__ Bw,
    const float* __restrict__ bias, float* outF, bf16* __restrict__ outB,
    const float* resid, const int M, const int N, const int K, const int extra, const int obst,
    const float* __restrict__ sw4, const float* __restrict__ gb4, const float* __restrict__ sb4) {
  constexpr int NW = WM * WN;
  constexpr int FM = BM / (WM * 16);
  constexpr int FN = BN / (WN * 16);
  constexpr int RPC = 512 / BK;
  constexpr int LA = (BM / RPC) / NW, LB = (BN / RPC) / NW;
  constexpr int KK = BK / 32;
  constexpr int TLOADS = LA + LB;
  static_assert(LA >= 1 && LB >= 1, "tile too small for staging split");
  static_assert((BM / RPC) % NW == 0 && (BN / RPC) % NW == 0, "staging split");
  __shared__ bf16 lsA[2][BM * BK];
  __shared__ bf16 lsB[2][BN * BK];
  const int tid = threadIdx.x;
  const int w = tid >> 6, lane = tid & 63;
  const int tm = blockIdx.x, tn = blockIdx.y;
  const int wr = w / WN, wc = w % WN;
  const int r16 = lane & 15, hi = lane >> 4;

  int srowoff, scoloff;
  if constexpr (BK == 64) {
    const int rr = lane >> 3, cs = lane & 7;
    srowoff = rr;
    scoloff = (cs ^ rr) * 8;
  } else {
    const int sr = lane >> 3, cs = lane & 7;
    const int idx = cs ^ (sr & 7);
    srowoff = sr * 2 + (idx >> 2);
    scoloff = (idx & 3) * 8;
  }

  const f32x4 fzero = {0.f, 0.f, 0.f, 0.f};
  f32x4 acc[FM][FN];
#pragma unroll
  for (int i = 0; i < FM; i++)
#pragma unroll
    for (int jj = 0; jj < FN; jj++) acc[i][jj] = fzero;

  const int NT = K / BK;

  auto stage = [&](int kt, int sel) {
#pragma unroll
    for (int q = 0; q < LA; q++) {
      const int g = w * LA + q;
      int m = tm * BM + g * RPC + srowoff;
      if (m > M - 1) m = M - 1;
      m += (m >> 10) * extra;
      gload_lds16(A + (size_t)m * K + (size_t)kt * BK + scoloff, &lsA[sel][g * 512]);
    }
#pragma unroll
    for (int q = 0; q < LB; q++) {
      const int g = w * LB + q;
      const int n = tn * BN + g * RPC + srowoff;
      gload_lds16(Bw + (size_t)n * K + (size_t)kt * BK + scoloff, &lsB[sel][g * 512]);
    }
  };

  auto frag = [&](const bf16* ls, int row, int cc) -> bf16x8 {
    if constexpr (BK == 64) {
      const int g = row >> 3, rr = row & 7;
      return *(const bf16x8*)&ls[g * 512 + rr * 64 + ((cc ^ rr) << 3)];
    } else {
      const int g = row >> 4, rr = row & 15, sr = rr >> 1;
      const int idx = ((rr & 1) << 2) | cc;
      return *(const bf16x8*)&ls[g * 512 + sr * 64 + ((idx ^ (sr & 7)) << 3)];
    }
  };

  stage(0, 0);
  for (int kt = 0; kt < NT; ++kt) {
    const int sel = kt & 1;
    if (kt + 1 < NT) {
      stage(kt + 1, sel ^ 1);
      vm_wait<TLOADS>();
    } else {
      vm_wait<0>();
    }
    __builtin_amdgcn_sched_barrier(0);
    __builtin_amdgcn_s_barrier();
    __builtin_amdgcn_sched_barrier(0);
#pragma unroll
    for (int kk = 0; kk < KK; ++kk) {
      bf16x8 af[FM], bfv[FN];
#pragma unroll
      for (int i = 0; i < FM; i++)
        af[i] = frag(lsA[sel], wr * (FM * 16) + i * 16 + r16, kk * 4 + hi);
#pragma unroll
      for (int jj = 0; jj < FN; jj++)
        bfv[jj] = frag(lsB[sel], wc * (FN * 16) + jj * 16 + r16, kk * 4 + hi);
#pragma unroll
      for (int i = 0; i < FM; i++)
#pragma unroll
        for (int jj = 0; jj < FN; jj++)
          acc[i][jj] = __builtin_amdgcn_mfma_f32_16x16x32_bf16(af[i], bfv[jj], acc[i][jj], 0, 0, 0);
    }
    if (kt + 1 < NT) {
      __builtin_amdgcn_sched_barrier(0);
      __builtin_amdgcn_s_barrier();
      __builtin_amdgcn_sched_barrier(0);
    }
  }

#pragma unroll
  for (int i = 0; i < FM; i++) {
#pragma unroll
    for (int r = 0; r < 4; r++) {
      const int m = tm * BM + wr * (FM * 16) + i * 16 + hi * 4 + r;
      if (m < M) {
#pragma unroll
        for (int jj = 0; jj < FN; jj++) {
          const int n = tn * BN + wc * (FN * 16) + jj * 16 + r16;
          float x = acc[i][jj][r];
          if (bias) x += bias[n];
          const size_t idx = (size_t)m * N + n;
          if (EPI == 0) {
            outF[idx] = x;
          } else if (EPI == 1) {
            outF[idx] = x;
            outB[(size_t)m * obst + n] = __float2bfloat16(x);
          } else if (EPI == 2) {
            outB[(size_t)m * obst + n] = __float2bfloat16(1.0f / (1.0f + __expf(-x)));
          } else if (EPI == 3) {
            outF[idx] = x + resid[idx];
          } else {
            const float a = 1.0f / (1.0f + __expf(-sw4[n]));
            const float om = 1.0f - a;
            outF[idx] = x + a * gb4[n] - om * sb4[n] + om * resid[idx];
          }
        }
      }
    }
  }
}

// ---------------- workspace layout ----------------
#define MB (size_t)(1u << 20)
static const size_t OFF_A = 0;          // 32MB: resT -> vbuf -> hbuf
static const size_t OFF_C = 32 * MB;    // 8MB : res1b / res2b
static const size_t OFF_E = 40 * MB;    // 6MB : weights bf16 (incl fused W' at W_GW, stride 1024)
static const size_t OFF_F = 46 * MB;    // 9MB : s2b (8200x512)
static const size_t OFF_G = 55 * MB;    // 17MB: combined A' grobC|seasC (8200x1024 bf16)
static const size_t OFF_H = 72 * MB;    // 16MB: res2f
static const size_t OFF_J = 88 * MB;    // comp
static const size_t OFF_K = 89 * MB;    // ubuf f32 (8192x64)

#define W_IN 0
#define W_OUT 262144
#define W_FF1 524288
#define W_FF2 1572864
#define W_GW 2621440

extern "C" void kernel_launch(void* const* d_in, const int* in_sizes, int n_in, void* d_out, int out_size,
                              void* d_ws, size_t ws_size, hipStream_t stream) {
  (void)in_sizes; (void)n_in; (void)out_size; (void)ws_size;
  const float* res = (const float*)d_in[0];
  const float* level = (const float*)d_in[1];
  const float* gl_z0 = (const float*)d_in[2];
  const float* gl_in_w = (const float*)d_in[3];
  const float* gl_in_b = (const float*)d_in[4];
  const float* gl_sw = (const float*)d_in[5];
  const float* gl_v0 = (const float*)d_in[6];
  const float* gl_out_w = (const float*)d_in[7];
  const float* gl_out_b = (const float*)d_in[8];
  const float* ll_sw = (const float*)d_in[9];
  const float* ll_v0 = (const float*)d_in[10];
  const float* ll_gw = (const float*)d_in[11];
  const float* ll_gb = (const float*)d_in[12];
  const float* ll_sw2 = (const float*)d_in[13];
  const float* ll_sb = (const float*)d_in[14];
  const float* ff_w1 = (const float*)d_in[15];
  const float* ff_w2 = (const float*)d_in[16];
  const float* n1_g = (const float*)d_in[17];
  const float* n1_b = (const float*)d_in[18];
  const float* n2_g = (const float*)d_in[19];
  const float* n2_b = (const float*)d_in[20];

  char* ws = (char*)d_ws;
  float* resT = (float*)(ws + OFF_A);
  float* vbuf = (float*)(ws + OFF_A);
  bf16* hbuf = (bf16*)(ws + OFF_A);
  bf16* res1b = (bf16*)(ws + OFF_C);
  bf16* res2b = (bf16*)(ws + OFF_C);
  bf16* wE = (bf16*)(ws + OFF_E);
  bf16* s2b = (bf16*)(ws + OFF_F);
  bf16* agC = (bf16*)(ws + OFF_G);     // combined [growth | season] bf16, stride 1024
  float* res2f = (float*)(ws + OFF_H);
  float* comp = (float*)(ws + OFF_J);
  float* ubuf = (float*)(ws + OFF_K);

  float* o_res = (float*)d_out;
  float* o_level = o_res + 4194304;
  float* o_growth = o_level + 524288;
  float* o_season = o_growth + 4198400;

  k_transpose<<<dim3(16, 32, 8), dim3(32, 8), 0, stream>>>(res, resT);
  k_fft_topk<<<2048, 256, 0, stream>>>(resT, comp);
  k_season<<<dim3(256, 8), 512, 0, stream>>>(comp, res, o_season, res1b, agC);
  k_cvt_all<<<(CVT_TOTAL / 4 + 255) / 256, 256, 0, stream>>>(gl_in_w, gl_out_w, ff_w1, ff_w2, ll_gw, ll_sw2, ll_sw, wE);
  // v = res1 @ gl_in_w^T + b
  k_gemm<64, 128, 64, 2, 2, 0><<<dim3(128, 4), 256, 0, stream>>>(
      res1b, wE + W_IN, gl_in_b, vbuf, nullptr, nullptr, 8192, 512, 512, 0, 512,
      nullptr, nullptr, nullptr);
  k_growth_scan2<<<64, 1024, 0, stream>>>(vbuf, gl_z0, gl_sw, gl_v0, s2b);
  // growth = s2 @ gl_out_w^T + b  (f32 -> o_growth; bf16 -> agC cols 0-511, stride 1024)
  k_gemm<64, 128, 64, 2, 2, 1><<<dim3(129, 4), 256, 0, stream>>>(
      s2b, wE + W_OUT, gl_out_b, o_growth, agC, nullptr, 8200, 512, 512, 0, 1024,
      nullptr, nullptr, nullptr);
  // LN1 from res1b (bf16) - agC growth rows (bf16, stride 1024, row phys+1)
  k_ln<0><<<8192, 128, 0, stream>>>(nullptr, res1b, agC, n1_g, n1_b, res2f, res2b);
  // FF1: 128x128 BK=32
  k_gemm<128, 128, 32, 2, 2, 2><<<dim3(64, 16), 256, 0, stream>>>(
      res2b, wE + W_FF1, nullptr, nullptr, hbuf, nullptr, 8192, 2048, 512, 0, 2048,
      nullptr, nullptr, nullptr);
  // FF2: 64x128 BK=64, K=2048
  k_gemm<64, 128, 64, 2, 2, 3><<<dim3(128, 4), 256, 0, stream>>>(
      hbuf, wE + W_FF2, nullptr, res2f, nullptr, res2f, 8192, 512, 2048, 0, 512,
      nullptr, nullptr, nullptr);
  k_ln<1><<<8192, 128, 0, stream>>>(res2f, nullptr, nullptr, n2_g, n2_b, o_res, nullptr);
  // merged level projection: u = A'(growth|season) @ W'^T + a*gb - om*sb + om*level
  k_gemm<64, 64, 64, 4, 1, 4><<<dim3(128, 1), 256, 0, stream>>>(
      agC, wE + W_GW, nullptr, ubuf, nullptr, level, 8192, 64, 1024, 1, 64,
      ll_sw, ll_gb, ll_sb);
  k_level_scan2<<<8, 1024, 0, stream>>>(ubuf, ll_sw, ll_v0, o_level);
}

// Round 17
// 214.028 us; speedup vs baseline: 1.0538x; 1.0053x over previous
//
#include <hip/hip_runtime.h>
#include <hip/hip_bf16.h>
#include <math.h>

#define B_ 8
#define T_ 1024
#define D_ 512
#define PRED 256
#define TP (T_ + PRED)
#define NH 8
#define DH 64
#define DFF 2048
#define CO 64
#define KSEL 8

typedef __hip_bfloat16 bf16;
using bf16x8 = __attribute__((ext_vector_type(8))) short;
using f32x4  = __attribute__((ext_vector_type(4))) float;

__device__ __forceinline__ void gload_lds16(const void* gp, void* lp) {
  __builtin_amdgcn_global_load_lds(
      (const __attribute__((address_space(1))) void*)gp,
      (__attribute__((address_space(3))) void*)lp, 16, 0, 0);
}

template <int N>
__device__ __forceinline__ void vm_wait() {
  if constexpr (N == 0)       asm volatile("s_waitcnt vmcnt(0)" ::: "memory");
  else if constexpr (N == 2)  asm volatile("s_waitcnt vmcnt(2)" ::: "memory");
  else if constexpr (N == 4)  asm volatile("s_waitcnt vmcnt(4)" ::: "memory");
  else if constexpr (N == 6)  asm volatile("s_waitcnt vmcnt(6)" ::: "memory");
  else if constexpr (N == 8)  asm volatile("s_waitcnt vmcnt(8)" ::: "memory");
  else if constexpr (N == 12) asm volatile("s_waitcnt vmcnt(12)" ::: "memory");
  else static_assert(N == 0, "unsupported vmcnt literal");
}

// ---------------- transpose res (b,T,D) -> resT (b,D,T) ----------------
__global__ __launch_bounds__(256) void k_transpose(const float* __restrict__ in, float* __restrict__ out) {
  __shared__ float tile[32][33];
  const int b = blockIdx.z;
  const int d0 = blockIdx.x * 32, t0 = blockIdx.y * 32;
  const int tx = threadIdx.x, ty = threadIdx.y;
  const float* src = in + ((size_t)b * T_ + t0) * D_ + d0;
#pragma unroll
  for (int i = 0; i < 32; i += 8) tile[ty + i][tx] = src[(size_t)(ty + i) * D_ + tx];
  __syncthreads();
  float* dst = out + ((size_t)b * D_ + d0) * T_ + t0;
#pragma unroll
  for (int i = 0; i < 32; i += 8) dst[(size_t)(ty + i) * T_ + tx] = tile[tx][ty + i];
}

// ---------------- 1024-pt real FFT, ONE WAVE per block (64 thr), radix-4 + in-reg top-8 ----------
// Single wave => __syncthreads degenerates to waitcnt (no cross-wave barrier coupling);
// 4096 independent blocks give ~14 waves/CU of pure TLP. Same validated radix-4 algebra.
__global__ __launch_bounds__(64) void k_fft_topk(const float* __restrict__ xt, float* __restrict__ comp) {
  __shared__ float2 bufA[512], bufB[512], tw[384];
  float* const mg = (float*)&bufA[0];
  const int j = threadIdx.x;
  const size_t bd = blockIdx.x;
  {
    const float c = -6.283185307179586f / 512.0f;
#pragma unroll
    for (int q = 0; q < 6; q++) {
      const int i = j + 64 * q;
      tw[i] = make_float2(__cosf(c * (float)i), __sinf(c * (float)i));
    }
  }
#pragma unroll
  for (int q = 0; q < 4; q++) {
    const float4 v = ((const float4*)(xt + bd * 1024))[j + 64 * q];
    bufA[2 * (j + 64 * q)] = make_float2(v.x, v.y);
    bufA[2 * (j + 64 * q) + 1] = make_float2(v.z, v.w);
  }
  __syncthreads();
  // stage 0: radix-2 (s=1), 4 butterflies/lane
#pragma unroll
  for (int q = 0; q < 4; q++) {
    const int p = j + 64 * q;
    const float2 w = tw[p];
    const float2 a = bufA[p], b = bufA[p + 256];
    bufB[2 * p] = make_float2(a.x + b.x, a.y + b.y);
    const float ex = a.x - b.x, ey = a.y - b.y;
    bufB[2 * p + 1] = make_float2(ex * w.x - ey * w.y, ex * w.y + ey * w.x);
  }
  __syncthreads();
  // stages 1..4: radix-4, 2 butterflies/lane
#pragma unroll
  for (int st = 0; st < 4; ++st) {
    const int lg = 1 + 2 * st;
    const int s = 1 << lg;
    const float2* src = (st & 1) ? (const float2*)bufA : (const float2*)bufB;
    float2* dst = (st & 1) ? (float2*)bufB : (float2*)bufA;
#pragma unroll
    for (int h = 0; h < 2; h++) {
      const int idx = j + 64 * h;
      const int p = idx >> lg;
      const int q = idx & (s - 1);
      const float2 x0 = src[idx];
      const float2 x1 = src[idx + 128];
      const float2 x2 = src[idx + 256];
      const float2 x3 = src[idx + 384];
      const float2 e0 = make_float2(x0.x + x2.x, x0.y + x2.y);
      const float2 e1 = make_float2(x0.x - x2.x, x0.y - x2.y);
      const float2 e2 = make_float2(x1.x + x3.x, x1.y + x3.y);
      const float2 e3 = make_float2(x1.x - x3.x, x1.y - x3.y);
      const float2 y0 = make_float2(e0.x + e2.x, e0.y + e2.y);
      const float2 y2 = make_float2(e0.x - e2.x, e0.y - e2.y);
      const float2 y1 = make_float2(e1.x + e3.y, e1.y - e3.x);
      const float2 y3 = make_float2(e1.x - e3.y, e1.y + e3.x);
      const int spi = p << lg;
      const float2 w1 = tw[spi], w2 = tw[2 * spi], w3 = tw[3 * spi];
      const int ob = q + (p << (lg + 2));
      dst[ob] = y0;
      dst[ob + s] = make_float2(y1.x * w1.x - y1.y * w1.y, y1.x * w1.y + y1.y * w1.x);
      dst[ob + 2 * s] = make_float2(y2.x * w2.x - y2.y * w2.y, y2.x * w2.y + y2.y * w2.x);
      dst[ob + 3 * s] = make_float2(y3.x * w3.x - y3.y * w3.y, y3.x * w3.y + y3.y * w3.x);
    }
    __syncthreads();
  }
  // result Z in bufB; bufA dead -> mag2 overlay. 8 bins/lane.
#pragma unroll
  for (int u = 0; u < 8; u++) {
    const int k = 1 + j + 64 * u;
    if (k <= 511) {
      const float2 zk = bufB[k];
      const float2 zm = bufB[(512 - k) & 511];
      const float Ex = 0.5f * (zk.x + zm.x), Ey = 0.5f * (zk.y - zm.y);
      const float Ox = 0.5f * (zk.y + zm.y), Oy = 0.5f * (zm.x - zk.x);
      const float ang = -(6.283185307179586f / 1024.0f) * (float)k;
      const float cs = __cosf(ang), sn = __sinf(ang);
      const float Xr = Ex + cs * Ox - sn * Oy;
      const float Xi = Ey + cs * Oy + sn * Ox;
      mg[k] = Xr * Xr + Xi * Xi;
    }
  }
  if (j == 0) mg[0] = -1.0f;
  __syncthreads();
  // in-register top-8: lane holds bins j, j+64, ..., j+448
  float cv[8];
#pragma unroll
  for (int u = 0; u < 8; u++) cv[u] = mg[j + 64 * u];
  int sel[8];
#pragma unroll
  for (int r = 0; r < KSEL; ++r) {
    float bv = cv[0];
    int bu = 0;
#pragma unroll
    for (int u = 1; u < 8; u++)
      if (cv[u] > bv) { bv = cv[u]; bu = u; }   // strict > keeps smallest bin on ties
    int bk = j + 64 * bu;
#pragma unroll
    for (int off = 32; off; off >>= 1) {
      const float ov = __shfl_down(bv, off);
      const int ok = __shfl_down(bk, off);
      if (ov > bv || (ov == bv && ok < bk)) { bv = ov; bk = ok; }
    }
    bk = __shfl(bk, 0);
    sel[r] = bk;
#pragma unroll
    for (int u = 0; u < 8; u++)
      if (bk == j + 64 * u) cv[u] = -2.0f;
  }
  if (j < KSEL) {
    int k = 0;
#pragma unroll
    for (int r = 0; r < KSEL; r++)
      if (j == r) k = sel[r];
    const float2 zk = bufB[k & 511];
    const float2 zm = bufB[(512 - k) & 511];
    const float Ex = 0.5f * (zk.x + zm.x), Ey = 0.5f * (zk.y - zm.y);
    const float Ox = 0.5f * (zk.y + zm.y), Oy = 0.5f * (zm.x - zk.x);
    const float ang = -(6.283185307179586f / 1024.0f) * (float)k;
    const float cs = __cosf(ang), sn = __sinf(ang);
    const float Xr = Ex + cs * Ox - sn * Oy;
    const float Xi = Ey + cs * Oy + sn * Ox;
    float* o = comp + bd * 24 + j * 3;
    o[0] = 2.0f * sqrtf(Xr * Xr + Xi * Xi) * (1.0f / 1024.0f);
    o[1] = (float)k;
    o[2] = atan2f(Xi, Xr);
  }
}

// ---------------- season synthesis + res1 = res - season ----------------
__global__ __launch_bounds__(512) void k_season(const float* __restrict__ comp, const float* __restrict__ res,
                                                float* __restrict__ season, bf16* __restrict__ res1b,
                                                bf16* __restrict__ seasC) {
  const int d = threadIdx.x;
  const int b = blockIdx.y;
  const int t0 = blockIdx.x * 5;
  float a_[8], kf_[8], ph_[8];
  const float* c = comp + ((size_t)b * 512 + d) * 24;
#pragma unroll
  for (int i = 0; i < 8; i++) { a_[i] = c[3 * i]; kf_[i] = c[3 * i + 1]; ph_[i] = c[3 * i + 2]; }
#pragma unroll
  for (int tt = 0; tt < 5; ++tt) {
    const int t = t0 + tt;
    float acc = 0.0f;
#pragma unroll
    for (int i = 0; i < 8; i++) {
      float fr = kf_[i] * (float)t * (1.0f / 1024.0f);
      fr -= floorf(fr);
      acc += a_[i] * __cosf(fmaf(6.283185307179586f, fr, ph_[i]));
    }
    season[((size_t)b * TP + t) * D_ + d] = acc;
    if (t < T_) {
      const float rr = res[((size_t)b * T_ + t) * D_ + d] - acc;
      res1b[((size_t)b * T_ + t) * D_ + d] = __float2bfloat16(rr);
      seasC[((size_t)b * 1025 + t) * 1024 + 512 + d] = __float2bfloat16(acc);
    }
  }
}

// ---------------- fused f32 -> bf16 weights; last two regions fused+scaled for level layer ----------------
#define CVT_TOTAL 2686976
__global__ __launch_bounds__(256) void k_cvt_all(const float* __restrict__ s0, const float* __restrict__ s1,
                                                 const float* __restrict__ s2_, const float* __restrict__ s3,
                                                 const float* __restrict__ s4, const float* __restrict__ s5,
                                                 const float* __restrict__ llsw, bf16* __restrict__ dst) {
  const int i = (blockIdx.x * 256 + threadIdx.x) * 4;
  if (i >= CVT_TOTAL) return;
  const float* src;
  int off;
  float scale = 1.0f;
  int di = i;
  if (i < 262144)       { src = s0;  off = i; }
  else if (i < 524288)  { src = s1;  off = i - 262144; }
  else if (i < 1572864) { src = s2_; off = i - 524288; }
  else if (i < 2621440) { src = s3;  off = i - 1572864; }
  else if (i < 2654208) {
    src = s4;  off = i - 2621440;
    const int c = off >> 9, k = off & 511;
    scale = 1.0f / (1.0f + __expf(-llsw[c]));
    di = 2621440 + c * 1024 + k;
  } else {
    src = s5;  off = i - 2654208;
    const int c = off >> 9, k = off & 511;
    const float alpha = 1.0f / (1.0f + __expf(-llsw[c]));
    scale = -(1.0f - alpha);
    di = 2621440 + c * 1024 + 512 + k;
  }
  const float4 v = *(const float4*)(src + off);
  bf16* o = dst + di;
  o[0] = __float2bfloat16(v.x * scale); o[1] = __float2bfloat16(v.y * scale);
  o[2] = __float2bfloat16(v.z * scale); o[3] = __float2bfloat16(v.w * scale);
}

// ---------------- growth exp-smooth blocked scan ----------------
__global__ __launch_bounds__(1024) void k_growth_scan2(const float* __restrict__ v, const float* __restrict__ z0,
                                                       const float* __restrict__ sw, const float* __restrict__ v0,
                                                       bf16* __restrict__ s2) {
  const int b = blockIdx.x >> 3;
  const int col = (blockIdx.x & 7) * 64 + (threadIdx.x & 63);
  const int w = threadIdx.x >> 6;
  const float alpha = 1.0f / (1.0f + expf(-sw[col >> 6]));
  const float om = 1.0f - alpha;
  float a64 = alpha;
#pragma unroll
  for (int i = 0; i < 6; i++) a64 *= a64;
  const float* vp = v + (size_t)b * T_ * D_ + col;
  float vprev = (w == 0) ? z0[col] : vp[(size_t)(64 * w - 1) * D_];
  float sloc = 0.0f;
#pragma unroll 8
  for (int j = 0; j < 64; j++) {
    const float nv = vp[(size_t)(64 * w + j) * D_];
    sloc = alpha * sloc + om * (nv - vprev);
    vprev = nv;
  }
  __shared__ float lb[16][64], lc[16][64];
  lb[w][threadIdx.x & 63] = sloc;
  __syncthreads();
  if (w == 0) {
    float s = v0[col];
#pragma unroll
    for (int k = 0; k < 16; k++) { lc[k][threadIdx.x & 63] = s; s = a64 * s + lb[k][threadIdx.x & 63]; }
  }
  __syncthreads();
  float s = lc[w][threadIdx.x & 63];
  vprev = (w == 0) ? z0[col] : vp[(size_t)(64 * w - 1) * D_];
  bf16* op = s2 + (size_t)b * (T_ + 1) * D_ + col;
  if (w == 0) op[0] = __float2bfloat16(v0[col]);
#pragma unroll 8
  for (int j = 0; j < 64; j++) {
    const float nv = vp[(size_t)(64 * w + j) * D_];
    s = alpha * s + om * (nv - vprev);
    vprev = nv;
    op[(size_t)(64 * w + j + 1) * D_] = __float2bfloat16(s);
  }
}

// ---------------- level exp-smooth blocked scan: u precomputed (ubuf), scan -> out ----------------
__global__ __launch_bounds__(1024) void k_level_scan2(const float* __restrict__ ubuf, const float* __restrict__ sw,
                                                      const float* __restrict__ v0, float* __restrict__ out) {
  const int b = blockIdx.x;
  const int w = threadIdx.x >> 6;
  const int c = threadIdx.x & 63;
  const float alpha = 1.0f / (1.0f + expf(-sw[c]));
  float a64 = alpha;
#pragma unroll
  for (int i = 0; i < 6; i++) a64 *= a64;
  const size_t base = ((size_t)b * T_ + 64 * w) * CO + c;
  float sloc = 0.0f;
#pragma unroll 8
  for (int j = 0; j < 64; j++) sloc = alpha * sloc + ubuf[base + (size_t)j * CO];
  __shared__ float lb[16][64], lc[16][64];
  lb[w][c] = sloc;
  __syncthreads();
  if (w == 0) {
    float s = v0[c];
#pragma unroll
    for (int k = 0; k < 16; k++) { lc[k][c] = s; s = a64 * s + lb[k][c]; }
  }
  __syncthreads();
  float s = lc[w][c];
#pragma unroll 8
  for (int j = 0; j < 64; j++) {
    const size_t idx = base + (size_t)j * CO;
    s = alpha * s + ubuf[idx];
    out[idx] = s;
  }
}

// ---------------- layer norm over D=512 ----------------
template <int MODE>
__global__ __launch_bounds__(128) void k_ln(const float* __restrict__ x1, const bf16* __restrict__ xb,
                                            const bf16* __restrict__ x3, const float* __restrict__ g,
                                            const float* __restrict__ be, float* __restrict__ outF,
                                            bf16* __restrict__ outB) {
  const int m = blockIdx.x, tid = threadIdx.x;
  const int b = m >> 10;
  float4 v;
  if (MODE == 0) {
    const ushort4 rb = ((const ushort4*)(xb + (size_t)m * D_))[tid];
    const ushort4 gr = ((const ushort4*)(x3 + ((size_t)(m + b + 1)) * 1024))[tid];
    v.x = __uint_as_float((unsigned)rb.x << 16) - __uint_as_float((unsigned)gr.x << 16);
    v.y = __uint_as_float((unsigned)rb.y << 16) - __uint_as_float((unsigned)gr.y << 16);
    v.z = __uint_as_float((unsigned)rb.z << 16) - __uint_as_float((unsigned)gr.z << 16);
    v.w = __uint_as_float((unsigned)rb.w << 16) - __uint_as_float((unsigned)gr.w << 16);
  } else {
    v = ((const float4*)(x1 + (size_t)m * D_))[tid];
  }
  float s = v.x + v.y + v.z + v.w;
  float s2 = v.x * v.x + v.y * v.y + v.z * v.z + v.w * v.w;
#pragma unroll
  for (int off = 32; off; off >>= 1) { s += __shfl_down(s, off); s2 += __shfl_down(s2, off); }
  __shared__ float p1[2], p2[2];
  if ((tid & 63) == 0) { p1[tid >> 6] = s; p2[tid >> 6] = s2; }
  __syncthreads();
  const float S = p1[0] + p1[1], S2 = p2[0] + p2[1];
  const float mu = S * (1.0f / 512.0f);
  const float rs = rsqrtf(fmaxf(S2 * (1.0f / 512.0f) - mu * mu, 0.0f) + 1e-5f);
  const float4 gg = ((const float4*)g)[tid], bb = ((const float4*)be)[tid];
  float4 o;
  o.x = (v.x - mu) * rs * gg.x + bb.x;
  o.y = (v.y - mu) * rs * gg.y + bb.y;
  o.z = (v.z - mu) * rs * gg.z + bb.z;
  o.w = (v.w - mu) * rs * gg.w + bb.w;
  ((float4*)(outF + (size_t)m * D_))[tid] = o;
  if (MODE == 0) {
    bf16* ob = outB + (size_t)m * D_ + tid * 4;
    ob[0] = __float2bfloat16(o.x); ob[1] = __float2bfloat16(o.y);
    ob[2] = __float2bfloat16(o.z); ob[3] = __float2bfloat16(o.w);
  }
}

// ---------------- bf16 MFMA GEMM, swizzled LDS + TRIPLE-buffer 2-ahead counted-vmcnt ------------
// tm = blockIdx.x (FASTEST): same-A-panel blocks co-locate per XCD (L2 A-hits).
// Pipeline: prologue stages tiles 0,1; iter kt stages kt+2 into buf[(kt+2)%3], waits
// vmcnt(2*TLOADS) (2 tiles in flight -> ~2 iterations of latency budget).
// Hazard: buf[(kt+2)%3] was last read in iter kt-1, whose end-barrier all waves passed.
template <int BM, int BN, int BK, int WM, int WN, int EPI>
__global__ __launch_bounds__(WM * WN * 64, 2) void k_gemm(
    const bf16* __restrict__ A, const bf16* __restrict__ Bw,
    const float* __restrict__ bias, float* outF, bf16* __restrict__ outB,
    const float* resid, const int M, const int N, const int K, const int extra, const int obst,
    const float* __restrict__ sw4, const float* __restrict__ gb4, const float* __restrict__ sb4) {
  constexpr int NW = WM * WN;
  constexpr int FM = BM / (WM * 16);
  constexpr int FN = BN / (WN * 16);
  constexpr int RPC = 512 / BK;
  constexpr int LA = (BM / RPC) / NW, LB = (BN / RPC) / NW;
  constexpr int KK = BK / 32;
  constexpr int TLOADS = LA + LB;
  static_assert(LA >= 1 && LB >= 1, "tile too small for staging split");
  static_assert((BM / RPC) % NW == 0 && (BN / RPC) % NW == 0, "staging split");
  __shared__ bf16 lsA[3][BM * BK];
  __shared__ bf16 lsB[3][BN * BK];
  const int tid = threadIdx.x;
  const int w = tid >> 6, lane = tid & 63;
  const int tm = blockIdx.x, tn = blockIdx.y;
  const int wr = w / WN, wc = w % WN;
  const int r16 = lane & 15, hi = lane >> 4;

  int srowoff, scoloff;
  if constexpr (BK == 64) {
    const int rr = lane >> 3, cs = lane & 7;
    srowoff = rr;
    scoloff = (cs ^ rr) * 8;
  } else {
    const int sr = lane >> 3, cs = lane & 7;
    const int idx = cs ^ (sr & 7);
    srowoff = sr * 2 + (idx >> 2);
    scoloff = (idx & 3) * 8;
  }

  const f32x4 fzero = {0.f, 0.f, 0.f, 0.f};
  f32x4 acc[FM][FN];
#pragma unroll
  for (int i = 0; i < FM; i++)
#pragma unroll
    for (int jj = 0; jj < FN; jj++) acc[i][jj] = fzero;

  const int NT = K / BK;

  auto stage = [&](int kt, int sel) {
#pragma unroll
    for (int q = 0; q < LA; q++) {
      const int g = w * LA + q;
      int m = tm * BM + g * RPC + srowoff;
      if (m > M - 1) m = M - 1;
      m += (m >> 10) * extra;
      gload_lds16(A + (size_t)m * K + (size_t)kt * BK + scoloff, &lsA[sel][g * 512]);
    }
#pragma unroll
    for (int q = 0; q < LB; q++) {
      const int g = w * LB + q;
      const int n = tn * BN + g * RPC + srowoff;
      gload_lds16(Bw + (size_t)n * K + (size_t)kt * BK + scoloff, &lsB[sel][g * 512]);
    }
  };

  auto frag = [&](const bf16* ls, int row, int cc) -> bf16x8 {
    if constexpr (BK == 64) {
      const int g = row >> 3, rr = row & 7;
      return *(const bf16x8*)&ls[g * 512 + rr * 64 + ((cc ^ rr) << 3)];
    } else {
      const int g = row >> 4, rr = row & 15, sr = rr >> 1;
      const int idx = ((rr & 1) << 2) | cc;
      return *(const bf16x8*)&ls[g * 512 + sr * 64 + ((idx ^ (sr & 7)) << 3)];
    }
  };

  stage(0, 0);
  if (1 < NT) stage(1, 1);
  for (int kt = 0; kt < NT; ++kt) {
    const int sel = kt % 3;
    if (kt + 2 < NT) {
      stage(kt + 2, (kt + 2) % 3);
      vm_wait<2 * TLOADS>();
    } else if (kt + 1 < NT) {
      vm_wait<TLOADS>();
    } else {
      vm_wait<0>();
    }
    __builtin_amdgcn_sched_barrier(0);
    __builtin_amdgcn_s_barrier();
    __builtin_amdgcn_sched_barrier(0);
#pragma unroll
    for (int kk = 0; kk < KK; ++kk) {
      bf16x8 af[FM], bfv[FN];
#pragma unroll
      for (int i = 0; i < FM; i++)
        af[i] = frag(lsA[sel], wr * (FM * 16) + i * 16 + r16, kk * 4 + hi);
#pragma unroll
      for (int jj = 0; jj < FN; jj++)
        bfv[jj] = frag(lsB[sel], wc * (FN * 16) + jj * 16 + r16, kk * 4 + hi);
#pragma unroll
      for (int i = 0; i < FM; i++)
#pragma unroll
        for (int jj = 0; jj < FN; jj++)
          acc[i][jj] = __builtin_amdgcn_mfma_f32_16x16x32_bf16(af[i], bfv[jj], acc[i][jj], 0, 0, 0);
    }
    if (kt + 1 < NT) {
      __builtin_amdgcn_sched_barrier(0);
      __builtin_amdgcn_s_barrier();
      __builtin_amdgcn_sched_barrier(0);
    }
  }

#pragma unroll
  for (int i = 0; i < FM; i++) {
#pragma unroll
    for (int r = 0; r < 4; r++) {
      const int m = tm * BM + wr * (FM * 16) + i * 16 + hi * 4 + r;
      if (m < M) {
#pragma unroll
        for (int jj = 0; jj < FN; jj++) {
          const int n = tn * BN + wc * (FN * 16) + jj * 16 + r16;
          float x = acc[i][jj][r];
          if (bias) x += bias[n];
          const size_t idx = (size_t)m * N + n;
          if (EPI == 0) {
            outF[idx] = x;
          } else if (EPI == 1) {
            outF[idx] = x;
            outB[(size_t)m * obst + n] = __float2bfloat16(x);
          } else if (EPI == 2) {
            outB[(size_t)m * obst + n] = __float2bfloat16(1.0f / (1.0f + __expf(-x)));
          } else if (EPI == 3) {
            outF[idx] = x + resid[idx];
          } else {
            const float a = 1.0f / (1.0f + __expf(-sw4[n]));
            const float om = 1.0f - a;
            outF[idx] = x + a * gb4[n] - om * sb4[n] + om * resid[idx];
          }
        }
      }
    }
  }
}

// ---------------- workspace layout ----------------
#define MB (size_t)(1u << 20)
static const size_t OFF_A = 0;          // 32MB: resT -> vbuf -> hbuf
static const size_t OFF_C = 32 * MB;    // 8MB : res1b / res2b
static const size_t OFF_E = 40 * MB;    // 6MB : weights bf16 (incl fused W' at W_GW, stride 1024)
static const size_t OFF_F = 46 * MB;    // 9MB : s2b (8200x512)
static const size_t OFF_G = 55 * MB;    // 17MB: combined A' grobC|seasC (8200x1024 bf16)
static const size_t OFF_H = 72 * MB;    // 16MB: res2f
static const size_t OFF_J = 88 * MB;    // comp
static const size_t OFF_K = 89 * MB;    // ubuf f32 (8192x64)

#define W_IN 0
#define W_OUT 262144
#define W_FF1 524288
#define W_FF2 1572864
#define W_GW 2621440

extern "C" void kernel_launch(void* const* d_in, const int* in_sizes, int n_in, void* d_out, int out_size,
                              void* d_ws, size_t ws_size, hipStream_t stream) {
  (void)in_sizes; (void)n_in; (void)out_size; (void)ws_size;
  const float* res = (const float*)d_in[0];
  const float* level = (const float*)d_in[1];
  const float* gl_z0 = (const float*)d_in[2];
  const float* gl_in_w = (const float*)d_in[3];
  const float* gl_in_b = (const float*)d_in[4];
  const float* gl_sw = (const float*)d_in[5];
  const float* gl_v0 = (const float*)d_in[6];
  const float* gl_out_w = (const float*)d_in[7];
  const float* gl_out_b = (const float*)d_in[8];
  const float* ll_sw = (const float*)d_in[9];
  const float* ll_v0 = (const float*)d_in[10];
  const float* ll_gw = (const float*)d_in[11];
  const float* ll_gb = (const float*)d_in[12];
  const float* ll_sw2 = (const float*)d_in[13];
  const float* ll_sb = (const float*)d_in[14];
  const float* ff_w1 = (const float*)d_in[15];
  const float* ff_w2 = (const float*)d_in[16];
  const float* n1_g = (const float*)d_in[17];
  const float* n1_b = (const float*)d_in[18];
  const float* n2_g = (const float*)d_in[19];
  const float* n2_b = (const float*)d_in[20];

  char* ws = (char*)d_ws;
  float* resT = (float*)(ws + OFF_A);
  float* vbuf = (float*)(ws + OFF_A);
  bf16* hbuf = (bf16*)(ws + OFF_A);
  bf16* res1b = (bf16*)(ws + OFF_C);
  bf16* res2b = (bf16*)(ws + OFF_C);
  bf16* wE = (bf16*)(ws + OFF_E);
  bf16* s2b = (bf16*)(ws + OFF_F);
  bf16* agC = (bf16*)(ws + OFF_G);
  float* res2f = (float*)(ws + OFF_H);
  float* comp = (float*)(ws + OFF_J);
  float* ubuf = (float*)(ws + OFF_K);

  float* o_res = (float*)d_out;
  float* o_level = o_res + 4194304;
  float* o_growth = o_level + 524288;
  float* o_season = o_growth + 4198400;

  k_transpose<<<dim3(16, 32, 8), dim3(32, 8), 0, stream>>>(res, resT);
  k_fft_topk<<<4096, 64, 0, stream>>>(resT, comp);
  k_season<<<dim3(256, 8), 512, 0, stream>>>(comp, res, o_season, res1b, agC);
  k_cvt_all<<<(CVT_TOTAL / 4 + 255) / 256, 256, 0, stream>>>(gl_in_w, gl_out_w, ff_w1, ff_w2, ll_gw, ll_sw2, ll_sw, wE);
  // v = res1 @ gl_in_w^T + b
  k_gemm<64, 128, 64, 2, 2, 0><<<dim3(128, 4), 256, 0, stream>>>(
      res1b, wE + W_IN, gl_in_b, vbuf, nullptr, nullptr, 8192, 512, 512, 0, 512,
      nullptr, nullptr, nullptr);
  k_growth_scan2<<<64, 1024, 0, stream>>>(vbuf, gl_z0, gl_sw, gl_v0, s2b);
  // growth = s2 @ gl_out_w^T + b  (f32 -> o_growth; bf16 -> agC cols 0-511, stride 1024)
  k_gemm<64, 128, 64, 2, 2, 1><<<dim3(129, 4), 256, 0, stream>>>(
      s2b, wE + W_OUT, gl_out_b, o_growth, agC, nullptr, 8200, 512, 512, 0, 1024,
      nullptr, nullptr, nullptr);
  // LN1 from res1b (bf16) - agC growth rows (bf16, stride 1024, row phys+1)
  k_ln<0><<<8192, 128, 0, stream>>>(nullptr, res1b, agC, n1_g, n1_b, res2f, res2b);
  // FF1: 128x128 BK=32
  k_gemm<128, 128, 32, 2, 2, 2><<<dim3(64, 16), 256, 0, stream>>>(
      res2b, wE + W_FF1, nullptr, nullptr, hbuf, nullptr, 8192, 2048, 512, 0, 2048,
      nullptr, nullptr, nullptr);
  // FF2: 64x128 BK=64, K=2048
  k_gemm<64, 128, 64, 2, 2, 3><<<dim3(128, 4), 256, 0, stream>>>(
      hbuf, wE + W_FF2, nullptr, res2f, nullptr, res2f, 8192, 512, 2048, 0, 512,
      nullptr, nullptr, nullptr);
  k_ln<1><<<8192, 128, 0, stream>>>(res2f, nullptr, nullptr, n2_g, n2_b, o_res, nullptr);
  // merged level projection: u = A'(growth|season) @ W'^T + a*gb - om*sb + om*level
  k_gemm<64, 64, 64, 4, 1, 4><<<dim3(128, 1), 256, 0, stream>>>(
      agC, wE + W_GW, nullptr, ubuf, nullptr, level, 8192, 64, 1024, 1, 64,
      ll_sw, ll_gb, ll_sb);
  k_level_scan2<<<8, 1024, 0, stream>>>(ubuf, ll_sw, ll_v0, o_level);
}